// Round 2
// baseline (664.517 us; speedup 1.0000x reference)
//
#include <hip/hip_runtime.h>
#include <math.h>

// Problem constants (fixed by setup_inputs)
#define BB 256      // batch
#define TT 256      // time steps
#define NQ 1000     // num_q
#define DK 128
#define DV 128
#define CC 32

__device__ __forceinline__ float fast_sigmoid(float x) {
    x = fminf(fmaxf(x, -30.f), 30.f);
    return 1.f / (1.f + __expf(-x));
}
__device__ __forceinline__ float fast_tanh(float x) {
    x = fminf(fmaxf(x, -15.f), 15.f);
    float t = __expf(2.f * x);
    return (t - 1.f) / (t + 1.f);
}

// ---------------------------------------------------------------------------
// Precompute kernel (unchanged from R1): per tile of 32 (b,t) pairs:
//   wt = softmax(kt @ Mk)            -> Wo  [pairs][32]
//   et = sigmoid(vt @ e_W + e_b)     -> Eo  [pairs][128]
//   at = tanh  (vt @ a_W + a_b)      -> Ao  [pairs][128]
//   ck = kt @ f_W[128:] + f_b        -> Ko  [pairs][128]
// ---------------------------------------------------------------------------

__device__ __forceinline__ void pre_gemm(
    const float* __restrict__ src,   // LDS [32][132]
    const float* __restrict__ Wm,    // global 128x128 row-major
    const float* __restrict__ bias,  // global [128]
    int act,                         // 0 sigmoid, 1 tanh, 2 none
    float* __restrict__ dst,         // global: [(base+p)*128 + d]
    size_t base, int tid)
{
    const int p0 = (tid >> 4) * 4;
    const int d0 = (tid & 15) * 8;
    float acc[4][8];
#pragma unroll
    for (int ii = 0; ii < 4; ++ii)
#pragma unroll
        for (int k = 0; k < 8; ++k) acc[ii][k] = 0.f;

    for (int j4 = 0; j4 < 128; j4 += 4) {
        float4 v[4];
#pragma unroll
        for (int ii = 0; ii < 4; ++ii)
            v[ii] = *(const float4*)&src[(p0 + ii) * 132 + j4];
#pragma unroll
        for (int jj = 0; jj < 4; ++jj) {
            float4 w0 = *(const float4*)&Wm[(j4 + jj) * 128 + d0];
            float4 w1 = *(const float4*)&Wm[(j4 + jj) * 128 + d0 + 4];
#pragma unroll
            for (int ii = 0; ii < 4; ++ii) {
                float vv = (jj == 0) ? v[ii].x : (jj == 1) ? v[ii].y
                         : (jj == 2) ? v[ii].z : v[ii].w;
                acc[ii][0] = fmaf(vv, w0.x, acc[ii][0]);
                acc[ii][1] = fmaf(vv, w0.y, acc[ii][1]);
                acc[ii][2] = fmaf(vv, w0.z, acc[ii][2]);
                acc[ii][3] = fmaf(vv, w0.w, acc[ii][3]);
                acc[ii][4] = fmaf(vv, w1.x, acc[ii][4]);
                acc[ii][5] = fmaf(vv, w1.y, acc[ii][5]);
                acc[ii][6] = fmaf(vv, w1.z, acc[ii][6]);
                acc[ii][7] = fmaf(vv, w1.w, acc[ii][7]);
            }
        }
    }
    float4 b0 = *(const float4*)&bias[d0];
    float4 b1 = *(const float4*)&bias[d0 + 4];
    float bb[8] = {b0.x, b0.y, b0.z, b0.w, b1.x, b1.y, b1.z, b1.w};
#pragma unroll
    for (int ii = 0; ii < 4; ++ii) {
        float o[8];
#pragma unroll
        for (int k = 0; k < 8; ++k) {
            float x = acc[ii][k] + bb[k];
            o[k] = (act == 0) ? fast_sigmoid(x) : (act == 1) ? fast_tanh(x) : x;
        }
        float* dp = dst + (base + (size_t)(p0 + ii)) * 128 + d0;
        *(float4*)dp       = make_float4(o[0], o[1], o[2], o[3]);
        *(float4*)(dp + 4) = make_float4(o[4], o[5], o[6], o[7]);
    }
}

__global__ __launch_bounds__(128) void pre_kernel(
    const int* __restrict__ skills, const int* __restrict__ responses,
    const float* __restrict__ k_emb, const float* __restrict__ v_emb,
    const float* __restrict__ Mk, const float* __restrict__ fW,
    const float* __restrict__ fb, const float* __restrict__ eW,
    const float* __restrict__ eb, const float* __restrict__ aW,
    const float* __restrict__ ab,
    float* __restrict__ Wo, float* __restrict__ Eo,
    float* __restrict__ Ao, float* __restrict__ Ko,
    float* __restrict__ outTrue,
    int t0, int Tc)
{
    const int tid = threadIdx.x;
    const size_t base = (size_t)blockIdx.x * 32;

    __shared__ float kt[32 * 132];
    __shared__ float vt[32 * 132];
    __shared__ float lg[32 * 33];
    __shared__ int sIdx[32], qIdx[32];

    if (tid < 32) {
        int flat = (int)base + tid;
        int b = flat / Tc, tcc = flat % Tc;
        int t = t0 + tcc;
        int gi = b * TT + t;
        int s = skills[gi];
        int r = responses[gi];
        int mr = (r > -1) ? r : 0;
        sIdx[tid] = s;
        qIdx[tid] = s + NQ * mr;
        if (t >= 1) outTrue[b * (TT - 1) + (t - 1)] = (float)r;
    }
    __syncthreads();

    for (int i = 0; i < 32; ++i) {
        kt[i * 132 + tid] = k_emb[(size_t)sIdx[i] * DK + tid];
        vt[i * 132 + tid] = v_emb[(size_t)qIdx[i] * DV + tid];
    }
    __syncthreads();

    // wt logits
    {
        const int p = tid >> 2;
        const int c0 = (tid & 3) * 8;
        float acc[8];
#pragma unroll
        for (int k = 0; k < 8; ++k) acc[k] = 0.f;
        for (int j4 = 0; j4 < 128; j4 += 4) {
            float4 kv = *(const float4*)&kt[p * 132 + j4];
#pragma unroll
            for (int jj = 0; jj < 4; ++jj) {
                float vv = (jj == 0) ? kv.x : (jj == 1) ? kv.y : (jj == 2) ? kv.z : kv.w;
                float4 m0 = *(const float4*)&Mk[(j4 + jj) * CC + c0];
                float4 m1 = *(const float4*)&Mk[(j4 + jj) * CC + c0 + 4];
                acc[0] = fmaf(vv, m0.x, acc[0]);
                acc[1] = fmaf(vv, m0.y, acc[1]);
                acc[2] = fmaf(vv, m0.z, acc[2]);
                acc[3] = fmaf(vv, m0.w, acc[3]);
                acc[4] = fmaf(vv, m1.x, acc[4]);
                acc[5] = fmaf(vv, m1.y, acc[5]);
                acc[6] = fmaf(vv, m1.z, acc[6]);
                acc[7] = fmaf(vv, m1.w, acc[7]);
            }
        }
#pragma unroll
        for (int k = 0; k < 8; ++k) lg[p * 33 + c0 + k] = acc[k];
    }
    __syncthreads();
    if (tid < 32) {
        float m = -1e30f;
#pragma unroll
        for (int c = 0; c < CC; ++c) m = fmaxf(m, lg[tid * 33 + c]);
        float ex[CC];
        float sum = 0.f;
#pragma unroll
        for (int c = 0; c < CC; ++c) { ex[c] = __expf(lg[tid * 33 + c] - m); sum += ex[c]; }
        float inv = 1.f / sum;
        float* wp = Wo + (base + tid) * CC;
#pragma unroll
        for (int c = 0; c < CC; c += 4)
            *(float4*)(wp + c) = make_float4(ex[c] * inv, ex[c + 1] * inv,
                                             ex[c + 2] * inv, ex[c + 3] * inv);
    }

    pre_gemm(vt, eW, eb, 0, Eo, base, tid);             // et = sigmoid
    pre_gemm(vt, aW, ab, 1, Ao, base, tid);             // at = tanh
    pre_gemm(kt, fW + 128 * 128, fb, 2, Ko, base, tid); // ck = linear
}

// ---------------------------------------------------------------------------
// Sequential kernel v2: one block per batch element, 128 threads, thread d
// owns Mv[:,d] (32 regs). Per step: rt_d = sum_c w_c*Mv[c][d] (w is
// wave-uniform), rank-1 update Mv[c] = fma(w_c, fma(-e_d, Mv[c], a_d), Mv[c]).
// ZERO barriers / LDS / shuffles — ft/pt are NOT recurrent, they moved to
// post_kernel. Depth-2 software pipeline on the W/E/A loads.
// ---------------------------------------------------------------------------

struct SeqOps { float4 w[8]; float e, a; };

__device__ __forceinline__ void seq_load(SeqOps& dst, const float4* __restrict__ W4,
                                         const float* __restrict__ Eb,
                                         const float* __restrict__ Ab, int t) {
#pragma unroll
    for (int q = 0; q < 8; ++q) dst.w[q] = W4[t * 8 + q];
    dst.e = Eb[(size_t)t * 128];
    dst.a = Ab[(size_t)t * 128];
}

__global__ __launch_bounds__(128, 1) void seq_kernel(
    const float* __restrict__ W, const float* __restrict__ E,
    const float* __restrict__ A, const float* __restrict__ Mv0,
    float* __restrict__ RT, float* __restrict__ MvWS,
    int Tc, int doInit, int doSave)
{
    const int b = blockIdx.x;
    const int d = threadIdx.x;

    float Mv[32];
    if (doInit) {
#pragma unroll
        for (int c = 0; c < 32; ++c) Mv[c] = Mv0[c * 128 + d];
    } else {
#pragma unroll
        for (int c = 0; c < 32; ++c) Mv[c] = MvWS[(size_t)b * 4096 + c * 128 + d];
    }

    const float4* W4 = (const float4*)(W + (size_t)b * Tc * CC);
    const float* Eb = E + (size_t)b * Tc * 128 + d;
    const float* Ab = A + (size_t)b * Tc * 128 + d;
    float* RTb = RT + (size_t)b * Tc * 128 + d;

    SeqOps buf[2];
    seq_load(buf[0], W4, Eb, Ab, 0);
    if (Tc > 1) seq_load(buf[1], W4, Eb, Ab, 1);

#pragma unroll 2
    for (int tc = 0; tc < Tc; ++tc) {
        SeqOps& cur = buf[tc & 1];

        // rt_d = sum_c w_c * Mv[c][d]  (uses Mv BEFORE update)
        float r0 = 0.f, r1 = 0.f, r2 = 0.f, r3 = 0.f;
#pragma unroll
        for (int q = 0; q < 8; ++q) {
            float4 w4 = cur.w[q];
            r0 = fmaf(w4.x, Mv[4 * q + 0], r0);
            r1 = fmaf(w4.y, Mv[4 * q + 1], r1);
            r2 = fmaf(w4.z, Mv[4 * q + 2], r2);
            r3 = fmaf(w4.w, Mv[4 * q + 3], r3);
        }
        RTb[(size_t)tc * 128] = (r0 + r1) + (r2 + r3);

        // Mv = Mv*(1 - w_c*e_d) + w_c*a_d  ==  fma(w, fma(-e, Mv, a), Mv)
        const float et = cur.e, av = cur.a;
#pragma unroll
        for (int q = 0; q < 8; ++q) {
            float4 w4 = cur.w[q];
            Mv[4*q+0] = fmaf(w4.x, fmaf(-et, Mv[4*q+0], av), Mv[4*q+0]);
            Mv[4*q+1] = fmaf(w4.y, fmaf(-et, Mv[4*q+1], av), Mv[4*q+1]);
            Mv[4*q+2] = fmaf(w4.z, fmaf(-et, Mv[4*q+2], av), Mv[4*q+2]);
            Mv[4*q+3] = fmaf(w4.w, fmaf(-et, Mv[4*q+3], av), Mv[4*q+3]);
        }

        // prefetch step tc+2 into the buffer we just consumed
        if (tc + 2 < Tc) seq_load(cur, W4, Eb, Ab, tc + 2);
    }

    if (doSave) {
#pragma unroll
        for (int c = 0; c < 32; ++c) MvWS[(size_t)b * 4096 + c * 128 + d] = Mv[c];
    }
}

// ---------------------------------------------------------------------------
// Post kernel: ft = tanh(rt @ f_W[:128] + ck), pt = sigmoid(ft . p_W + p_b).
// Tile of 32 (b,t) rows per block, 128 threads, 4x8 register tile; p-dot
// reduced in-register across the 16 lanes sharing a pair group.
// ---------------------------------------------------------------------------

__global__ __launch_bounds__(128) void post_kernel(
    const float* __restrict__ RT, const float* __restrict__ Ko,
    const float* __restrict__ fW, const float* __restrict__ pW,
    const float* __restrict__ pb,
    float* __restrict__ pred, int t0, int Tc)
{
    const int tid = threadIdx.x;
    const size_t base = (size_t)blockIdx.x * 32;

    __shared__ float rt[32 * 132];
    for (int i = 0; i < 32; ++i)
        rt[i * 132 + tid] = RT[(base + i) * 128 + tid];
    __syncthreads();

    const int p0 = (tid >> 4) * 4;
    const int d0 = (tid & 15) * 8;
    float acc[4][8];
#pragma unroll
    for (int ii = 0; ii < 4; ++ii)
#pragma unroll
        for (int k = 0; k < 8; ++k) acc[ii][k] = 0.f;

    for (int j4 = 0; j4 < 128; j4 += 4) {
        float4 v[4];
#pragma unroll
        for (int ii = 0; ii < 4; ++ii)
            v[ii] = *(const float4*)&rt[(p0 + ii) * 132 + j4];
#pragma unroll
        for (int jj = 0; jj < 4; ++jj) {
            float4 w0 = *(const float4*)&fW[(j4 + jj) * 128 + d0];
            float4 w1 = *(const float4*)&fW[(j4 + jj) * 128 + d0 + 4];
#pragma unroll
            for (int ii = 0; ii < 4; ++ii) {
                float vv = (jj == 0) ? v[ii].x : (jj == 1) ? v[ii].y
                         : (jj == 2) ? v[ii].z : v[ii].w;
                acc[ii][0] = fmaf(vv, w0.x, acc[ii][0]);
                acc[ii][1] = fmaf(vv, w0.y, acc[ii][1]);
                acc[ii][2] = fmaf(vv, w0.z, acc[ii][2]);
                acc[ii][3] = fmaf(vv, w0.w, acc[ii][3]);
                acc[ii][4] = fmaf(vv, w1.x, acc[ii][4]);
                acc[ii][5] = fmaf(vv, w1.y, acc[ii][5]);
                acc[ii][6] = fmaf(vv, w1.z, acc[ii][6]);
                acc[ii][7] = fmaf(vv, w1.w, acc[ii][7]);
            }
        }
    }

    float4 pw0 = *(const float4*)&pW[d0];
    float4 pw1 = *(const float4*)&pW[d0 + 4];
    float pwv[8] = {pw0.x, pw0.y, pw0.z, pw0.w, pw1.x, pw1.y, pw1.z, pw1.w};

    float part[4];
#pragma unroll
    for (int ii = 0; ii < 4; ++ii) {
        const float* ckp = Ko + (base + (size_t)(p0 + ii)) * 128 + d0;
        float4 c0 = *(const float4*)ckp;
        float4 c1 = *(const float4*)(ckp + 4);
        float ck[8] = {c0.x, c0.y, c0.z, c0.w, c1.x, c1.y, c1.z, c1.w};
        float s = 0.f;
#pragma unroll
        for (int k = 0; k < 8; ++k) {
            float ft = fast_tanh(acc[ii][k] + ck[k]);
            s = fmaf(ft, pwv[k], s);
        }
        part[ii] = s;
    }
#pragma unroll
    for (int off = 1; off < 16; off <<= 1)
#pragma unroll
        for (int ii = 0; ii < 4; ++ii)
            part[ii] += __shfl_xor(part[ii], off, 64);

    if ((tid & 15) == 0) {
        float pbv = pb[0];
#pragma unroll
        for (int ii = 0; ii < 4; ++ii) {
            int flat = (int)base + p0 + ii;
            int bb = flat / Tc, tcc = flat % Tc;
            int t = t0 + tcc;
            if (t < TT - 1)
                pred[bb * (TT - 1) + t] = fast_sigmoid(part[ii] + pbv);
        }
    }
}

// ---------------------------------------------------------------------------

extern "C" void kernel_launch(void* const* d_in, const int* in_sizes, int n_in,
                              void* d_out, int out_size, void* d_ws, size_t ws_size,
                              hipStream_t stream) {
    const int*   skills    = (const int*)d_in[0];
    const int*   responses = (const int*)d_in[1];
    const float* k_emb     = (const float*)d_in[2];
    const float* v_emb     = (const float*)d_in[3];
    const float* Mk        = (const float*)d_in[4];
    const float* Mv0       = (const float*)d_in[5];
    const float* f_W       = (const float*)d_in[6];
    const float* f_b       = (const float*)d_in[7];
    const float* p_W       = (const float*)d_in[8];
    const float* p_b       = (const float*)d_in[9];
    const float* e_W       = (const float*)d_in[10];
    const float* e_b       = (const float*)d_in[11];
    const float* a_W       = (const float*)d_in[12];
    const float* a_b       = (const float*)d_in[13];

    float* pred    = (float*)d_out;                 // [256][255]
    float* outTrue = pred + BB * (TT - 1);          // [256][255]

    // choose time-chunk so scratch fits ws: W + E + A + CK + RT (+ Mv carry)
    int Tc = TT;
    for (;;) {
        size_t need = (size_t)BB * Tc * (CC + 4 * 128) * sizeof(float);
        if (Tc < TT) need += (size_t)BB * 4096 * sizeof(float);
        if (need <= ws_size || Tc <= 32) break;
        Tc >>= 1;
    }

    float* Wo   = (float*)d_ws;
    float* Eo   = Wo + (size_t)BB * Tc * CC;
    float* Ao   = Eo + (size_t)BB * Tc * 128;
    float* Ko   = Ao + (size_t)BB * Tc * 128;
    float* RTo  = Ko + (size_t)BB * Tc * 128;
    float* MvWS = RTo + (size_t)BB * Tc * 128;

    for (int t0 = 0; t0 < TT; t0 += Tc) {
        pre_kernel<<<(BB * Tc) / 32, 128, 0, stream>>>(
            skills, responses, k_emb, v_emb, Mk, f_W, f_b, e_W, e_b, a_W, a_b,
            Wo, Eo, Ao, Ko, outTrue, t0, Tc);
        seq_kernel<<<BB, 128, 0, stream>>>(
            Wo, Eo, Ao, Mv0, RTo, MvWS,
            Tc, t0 == 0 ? 1 : 0, (t0 + Tc < TT) ? 1 : 0);
        post_kernel<<<(BB * Tc) / 32, 128, 0, stream>>>(
            RTo, Ko, f_W, p_W, p_b, pred, t0, Tc);
    }
}

// Round 3
// 408.042 us; speedup vs baseline: 1.6285x; 1.6285x over previous
//
#include <hip/hip_runtime.h>
#include <math.h>

// Problem constants (fixed by setup_inputs)
#define BB 256      // batch
#define TT 256      // time steps
#define NQ 1000     // num_q
#define DK 128
#define DV 128
#define CC 32

__device__ __forceinline__ float fast_sigmoid(float x) {
    x = fminf(fmaxf(x, -30.f), 30.f);
    return 1.f / (1.f + __expf(-x));
}
__device__ __forceinline__ float fast_tanh(float x) {
    x = fminf(fmaxf(x, -15.f), 15.f);
    float t = __expf(2.f * x);
    return (t - 1.f) / (t + 1.f);
}

// ---------------------------------------------------------------------------
// Precompute kernel (unchanged): per tile of 32 (b,t) pairs:
//   wt = softmax(kt @ Mk)            -> Wo  [pairs][32]
//   et = sigmoid(vt @ e_W + e_b)     -> Eo  [pairs][128]
//   at = tanh  (vt @ a_W + a_b)      -> Ao  [pairs][128]
//   ck = kt @ f_W[128:] + f_b        -> Ko  [pairs][128]
// ---------------------------------------------------------------------------

__device__ __forceinline__ void pre_gemm(
    const float* __restrict__ src,   // LDS [32][132]
    const float* __restrict__ Wm,    // global 128x128 row-major
    const float* __restrict__ bias,  // global [128]
    int act,                         // 0 sigmoid, 1 tanh, 2 none
    float* __restrict__ dst,         // global: [(base+p)*128 + d]
    size_t base, int tid)
{
    const int p0 = (tid >> 4) * 4;
    const int d0 = (tid & 15) * 8;
    float acc[4][8];
#pragma unroll
    for (int ii = 0; ii < 4; ++ii)
#pragma unroll
        for (int k = 0; k < 8; ++k) acc[ii][k] = 0.f;

    for (int j4 = 0; j4 < 128; j4 += 4) {
        float4 v[4];
#pragma unroll
        for (int ii = 0; ii < 4; ++ii)
            v[ii] = *(const float4*)&src[(p0 + ii) * 132 + j4];
#pragma unroll
        for (int jj = 0; jj < 4; ++jj) {
            float4 w0 = *(const float4*)&Wm[(j4 + jj) * 128 + d0];
            float4 w1 = *(const float4*)&Wm[(j4 + jj) * 128 + d0 + 4];
#pragma unroll
            for (int ii = 0; ii < 4; ++ii) {
                float vv = (jj == 0) ? v[ii].x : (jj == 1) ? v[ii].y
                         : (jj == 2) ? v[ii].z : v[ii].w;
                acc[ii][0] = fmaf(vv, w0.x, acc[ii][0]);
                acc[ii][1] = fmaf(vv, w0.y, acc[ii][1]);
                acc[ii][2] = fmaf(vv, w0.z, acc[ii][2]);
                acc[ii][3] = fmaf(vv, w0.w, acc[ii][3]);
                acc[ii][4] = fmaf(vv, w1.x, acc[ii][4]);
                acc[ii][5] = fmaf(vv, w1.y, acc[ii][5]);
                acc[ii][6] = fmaf(vv, w1.z, acc[ii][6]);
                acc[ii][7] = fmaf(vv, w1.w, acc[ii][7]);
            }
        }
    }
    float4 b0 = *(const float4*)&bias[d0];
    float4 b1 = *(const float4*)&bias[d0 + 4];
    float bb[8] = {b0.x, b0.y, b0.z, b0.w, b1.x, b1.y, b1.z, b1.w};
#pragma unroll
    for (int ii = 0; ii < 4; ++ii) {
        float o[8];
#pragma unroll
        for (int k = 0; k < 8; ++k) {
            float x = acc[ii][k] + bb[k];
            o[k] = (act == 0) ? fast_sigmoid(x) : (act == 1) ? fast_tanh(x) : x;
        }
        float* dp = dst + (base + (size_t)(p0 + ii)) * 128 + d0;
        *(float4*)dp       = make_float4(o[0], o[1], o[2], o[3]);
        *(float4*)(dp + 4) = make_float4(o[4], o[5], o[6], o[7]);
    }
}

__global__ __launch_bounds__(128) void pre_kernel(
    const int* __restrict__ skills, const int* __restrict__ responses,
    const float* __restrict__ k_emb, const float* __restrict__ v_emb,
    const float* __restrict__ Mk, const float* __restrict__ fW,
    const float* __restrict__ fb, const float* __restrict__ eW,
    const float* __restrict__ eb, const float* __restrict__ aW,
    const float* __restrict__ ab,
    float* __restrict__ Wo, float* __restrict__ Eo,
    float* __restrict__ Ao, float* __restrict__ Ko,
    float* __restrict__ outTrue,
    int t0, int Tc)
{
    const int tid = threadIdx.x;
    const size_t base = (size_t)blockIdx.x * 32;

    __shared__ float kt[32 * 132];
    __shared__ float vt[32 * 132];
    __shared__ float lg[32 * 33];
    __shared__ int sIdx[32], qIdx[32];

    if (tid < 32) {
        int flat = (int)base + tid;
        int b = flat / Tc, tcc = flat % Tc;
        int t = t0 + tcc;
        int gi = b * TT + t;
        int s = skills[gi];
        int r = responses[gi];
        int mr = (r > -1) ? r : 0;
        sIdx[tid] = s;
        qIdx[tid] = s + NQ * mr;
        if (t >= 1) outTrue[b * (TT - 1) + (t - 1)] = (float)r;
    }
    __syncthreads();

    for (int i = 0; i < 32; ++i) {
        kt[i * 132 + tid] = k_emb[(size_t)sIdx[i] * DK + tid];
        vt[i * 132 + tid] = v_emb[(size_t)qIdx[i] * DV + tid];
    }
    __syncthreads();

    // wt logits
    {
        const int p = tid >> 2;
        const int c0 = (tid & 3) * 8;
        float acc[8];
#pragma unroll
        for (int k = 0; k < 8; ++k) acc[k] = 0.f;
        for (int j4 = 0; j4 < 128; j4 += 4) {
            float4 kv = *(const float4*)&kt[p * 132 + j4];
#pragma unroll
            for (int jj = 0; jj < 4; ++jj) {
                float vv = (jj == 0) ? kv.x : (jj == 1) ? kv.y : (jj == 2) ? kv.z : kv.w;
                float4 m0 = *(const float4*)&Mk[(j4 + jj) * CC + c0];
                float4 m1 = *(const float4*)&Mk[(j4 + jj) * CC + c0 + 4];
                acc[0] = fmaf(vv, m0.x, acc[0]);
                acc[1] = fmaf(vv, m0.y, acc[1]);
                acc[2] = fmaf(vv, m0.z, acc[2]);
                acc[3] = fmaf(vv, m0.w, acc[3]);
                acc[4] = fmaf(vv, m1.x, acc[4]);
                acc[5] = fmaf(vv, m1.y, acc[5]);
                acc[6] = fmaf(vv, m1.z, acc[6]);
                acc[7] = fmaf(vv, m1.w, acc[7]);
            }
        }
#pragma unroll
        for (int k = 0; k < 8; ++k) lg[p * 33 + c0 + k] = acc[k];
    }
    __syncthreads();
    if (tid < 32) {
        float m = -1e30f;
#pragma unroll
        for (int c = 0; c < CC; ++c) m = fmaxf(m, lg[tid * 33 + c]);
        float ex[CC];
        float sum = 0.f;
#pragma unroll
        for (int c = 0; c < CC; ++c) { ex[c] = __expf(lg[tid * 33 + c] - m); sum += ex[c]; }
        float inv = 1.f / sum;
        float* wp = Wo + (base + tid) * CC;
#pragma unroll
        for (int c = 0; c < CC; c += 4)
            *(float4*)(wp + c) = make_float4(ex[c] * inv, ex[c + 1] * inv,
                                             ex[c + 2] * inv, ex[c + 3] * inv);
    }

    pre_gemm(vt, eW, eb, 0, Eo, base, tid);             // et = sigmoid
    pre_gemm(vt, aW, ab, 1, Ao, base, tid);             // at = tanh
    pre_gemm(kt, fW + 128 * 128, fb, 2, Ko, base, tid); // ck = linear
}

// ---------------------------------------------------------------------------
// Sequential kernel v3: one block per batch element, 128 threads, thread d
// owns Mv[:,d] (32 regs). ZERO barriers / LDS / shuffles.
//
// R2 lesson: SeqOps buf[2] + `buf[tc&1]` reference defeated SROA -> the whole
// pipeline buffer went to scratch (VGPR_Count=56), making every step ~4
// serialized memory round-trips (3830 cyc/step). v3 uses three NAMED buffer
// structs, only compile-time indices, manual unroll-by-3 rotation ->
// everything in VGPRs; prefetch->use distance = 2 full steps (~450 cyc),
// covering L2/L3 latency.
// ---------------------------------------------------------------------------

struct Ops { float4 w[8]; float e, a; };

#define SEQ_LOAD(B, t) do {                                                   \
    int _tt = (t) < Tc ? (t) : (Tc - 1);                                      \
    _Pragma("unroll")                                                         \
    for (int q = 0; q < 8; ++q) B.w[q] = W4[(size_t)_tt * 8 + q];             \
    B.e = Eb[(size_t)_tt * 128];                                              \
    B.a = Ab[(size_t)_tt * 128];                                              \
} while (0)

#define SEQ_STEP(B, t) do {                                                   \
    if ((t) < Tc) {                                                           \
        float r0 = 0.f, r1 = 0.f, r2 = 0.f, r3 = 0.f;                         \
        _Pragma("unroll")                                                     \
        for (int q = 0; q < 8; ++q) {                                         \
            float4 w4 = B.w[q];                                               \
            r0 = fmaf(w4.x, Mv[4*q+0], r0);                                   \
            r1 = fmaf(w4.y, Mv[4*q+1], r1);                                   \
            r2 = fmaf(w4.z, Mv[4*q+2], r2);                                   \
            r3 = fmaf(w4.w, Mv[4*q+3], r3);                                   \
        }                                                                     \
        RTb[(size_t)(t) * 128] = (r0 + r1) + (r2 + r3);                       \
        const float _e = B.e, _a = B.a;                                       \
        _Pragma("unroll")                                                     \
        for (int q = 0; q < 8; ++q) {                                         \
            float4 w4 = B.w[q];                                               \
            Mv[4*q+0] = fmaf(w4.x, fmaf(-_e, Mv[4*q+0], _a), Mv[4*q+0]);      \
            Mv[4*q+1] = fmaf(w4.y, fmaf(-_e, Mv[4*q+1], _a), Mv[4*q+1]);      \
            Mv[4*q+2] = fmaf(w4.z, fmaf(-_e, Mv[4*q+2], _a), Mv[4*q+2]);      \
            Mv[4*q+3] = fmaf(w4.w, fmaf(-_e, Mv[4*q+3], _a), Mv[4*q+3]);      \
        }                                                                     \
    }                                                                         \
} while (0)

__global__ __launch_bounds__(128, 1) void seq_kernel(
    const float* __restrict__ W, const float* __restrict__ E,
    const float* __restrict__ A, const float* __restrict__ Mv0,
    float* __restrict__ RT, float* __restrict__ MvWS,
    int Tc, int doInit, int doSave)
{
    const int b = blockIdx.x;
    const int d = threadIdx.x;

    float Mv[32];
    if (doInit) {
#pragma unroll
        for (int c = 0; c < 32; ++c) Mv[c] = Mv0[c * 128 + d];
    } else {
#pragma unroll
        for (int c = 0; c < 32; ++c) Mv[c] = MvWS[(size_t)b * 4096 + c * 128 + d];
    }

    const float4* __restrict__ W4 = (const float4*)(W + (size_t)b * Tc * CC);
    const float* __restrict__ Eb = E + (size_t)b * Tc * 128 + d;
    const float* __restrict__ Ab = A + (size_t)b * Tc * 128 + d;
    float* __restrict__ RTb = RT + (size_t)b * Tc * 128 + d;

    Ops B0, B1, B2;
    SEQ_LOAD(B0, 0);
    SEQ_LOAD(B1, 1);
    SEQ_LOAD(B2, 2);

    for (int tc = 0; tc < Tc; tc += 3) {
        SEQ_STEP(B0, tc);     SEQ_LOAD(B0, tc + 3);
        SEQ_STEP(B1, tc + 1); SEQ_LOAD(B1, tc + 4);
        SEQ_STEP(B2, tc + 2); SEQ_LOAD(B2, tc + 5);
    }

    if (doSave) {
#pragma unroll
        for (int c = 0; c < 32; ++c) MvWS[(size_t)b * 4096 + c * 128 + d] = Mv[c];
    }
}

// ---------------------------------------------------------------------------
// Post kernel (unchanged): ft = tanh(rt @ f_W[:128] + ck),
// pt = sigmoid(ft . p_W + p_b).
// ---------------------------------------------------------------------------

__global__ __launch_bounds__(128) void post_kernel(
    const float* __restrict__ RT, const float* __restrict__ Ko,
    const float* __restrict__ fW, const float* __restrict__ pW,
    const float* __restrict__ pb,
    float* __restrict__ pred, int t0, int Tc)
{
    const int tid = threadIdx.x;
    const size_t base = (size_t)blockIdx.x * 32;

    __shared__ float rt[32 * 132];
    for (int i = 0; i < 32; ++i)
        rt[i * 132 + tid] = RT[(base + i) * 128 + tid];
    __syncthreads();

    const int p0 = (tid >> 4) * 4;
    const int d0 = (tid & 15) * 8;
    float acc[4][8];
#pragma unroll
    for (int ii = 0; ii < 4; ++ii)
#pragma unroll
        for (int k = 0; k < 8; ++k) acc[ii][k] = 0.f;

    for (int j4 = 0; j4 < 128; j4 += 4) {
        float4 v[4];
#pragma unroll
        for (int ii = 0; ii < 4; ++ii)
            v[ii] = *(const float4*)&rt[(p0 + ii) * 132 + j4];
#pragma unroll
        for (int jj = 0; jj < 4; ++jj) {
            float4 w0 = *(const float4*)&fW[(j4 + jj) * 128 + d0];
            float4 w1 = *(const float4*)&fW[(j4 + jj) * 128 + d0 + 4];
#pragma unroll
            for (int ii = 0; ii < 4; ++ii) {
                float vv = (jj == 0) ? v[ii].x : (jj == 1) ? v[ii].y
                         : (jj == 2) ? v[ii].z : v[ii].w;
                acc[ii][0] = fmaf(vv, w0.x, acc[ii][0]);
                acc[ii][1] = fmaf(vv, w0.y, acc[ii][1]);
                acc[ii][2] = fmaf(vv, w0.z, acc[ii][2]);
                acc[ii][3] = fmaf(vv, w0.w, acc[ii][3]);
                acc[ii][4] = fmaf(vv, w1.x, acc[ii][4]);
                acc[ii][5] = fmaf(vv, w1.y, acc[ii][5]);
                acc[ii][6] = fmaf(vv, w1.z, acc[ii][6]);
                acc[ii][7] = fmaf(vv, w1.w, acc[ii][7]);
            }
        }
    }

    float4 pw0 = *(const float4*)&pW[d0];
    float4 pw1 = *(const float4*)&pW[d0 + 4];
    float pwv[8] = {pw0.x, pw0.y, pw0.z, pw0.w, pw1.x, pw1.y, pw1.z, pw1.w};

    float part[4];
#pragma unroll
    for (int ii = 0; ii < 4; ++ii) {
        const float* ckp = Ko + (base + (size_t)(p0 + ii)) * 128 + d0;
        float4 c0 = *(const float4*)ckp;
        float4 c1 = *(const float4*)(ckp + 4);
        float ck[8] = {c0.x, c0.y, c0.z, c0.w, c1.x, c1.y, c1.z, c1.w};
        float s = 0.f;
#pragma unroll
        for (int k = 0; k < 8; ++k) {
            float ft = fast_tanh(acc[ii][k] + ck[k]);
            s = fmaf(ft, pwv[k], s);
        }
        part[ii] = s;
    }
#pragma unroll
    for (int off = 1; off < 16; off <<= 1)
#pragma unroll
        for (int ii = 0; ii < 4; ++ii)
            part[ii] += __shfl_xor(part[ii], off, 64);

    if ((tid & 15) == 0) {
        float pbv = pb[0];
#pragma unroll
        for (int ii = 0; ii < 4; ++ii) {
            int flat = (int)base + p0 + ii;
            int bb = flat / Tc, tcc = flat % Tc;
            int t = t0 + tcc;
            if (t < TT - 1)
                pred[bb * (TT - 1) + t] = fast_sigmoid(part[ii] + pbv);
        }
    }
}

// ---------------------------------------------------------------------------

extern "C" void kernel_launch(void* const* d_in, const int* in_sizes, int n_in,
                              void* d_out, int out_size, void* d_ws, size_t ws_size,
                              hipStream_t stream) {
    const int*   skills    = (const int*)d_in[0];
    const int*   responses = (const int*)d_in[1];
    const float* k_emb     = (const float*)d_in[2];
    const float* v_emb     = (const float*)d_in[3];
    const float* Mk        = (const float*)d_in[4];
    const float* Mv0       = (const float*)d_in[5];
    const float* f_W       = (const float*)d_in[6];
    const float* f_b       = (const float*)d_in[7];
    const float* p_W       = (const float*)d_in[8];
    const float* p_b       = (const float*)d_in[9];
    const float* e_W       = (const float*)d_in[10];
    const float* e_b       = (const float*)d_in[11];
    const float* a_W       = (const float*)d_in[12];
    const float* a_b       = (const float*)d_in[13];

    float* pred    = (float*)d_out;                 // [256][255]
    float* outTrue = pred + BB * (TT - 1);          // [256][255]

    // choose time-chunk so scratch fits ws: W + E + A + CK + RT (+ Mv carry)
    int Tc = TT;
    for (;;) {
        size_t need = (size_t)BB * Tc * (CC + 4 * 128) * sizeof(float);
        if (Tc < TT) need += (size_t)BB * 4096 * sizeof(float);
        if (need <= ws_size || Tc <= 32) break;
        Tc >>= 1;
    }

    float* Wo   = (float*)d_ws;
    float* Eo   = Wo + (size_t)BB * Tc * CC;
    float* Ao   = Eo + (size_t)BB * Tc * 128;
    float* Ko   = Ao + (size_t)BB * Tc * 128;
    float* RTo  = Ko + (size_t)BB * Tc * 128;
    float* MvWS = RTo + (size_t)BB * Tc * 128;

    for (int t0 = 0; t0 < TT; t0 += Tc) {
        pre_kernel<<<(BB * Tc) / 32, 128, 0, stream>>>(
            skills, responses, k_emb, v_emb, Mk, f_W, f_b, e_W, e_b, a_W, a_b,
            Wo, Eo, Ao, Ko, outTrue, t0, Tc);
        seq_kernel<<<BB, 128, 0, stream>>>(
            Wo, Eo, Ao, Mv0, RTo, MvWS,
            Tc, t0 == 0 ? 1 : 0, (t0 + Tc < TT) ? 1 : 0);
        post_kernel<<<(BB * Tc) / 32, 128, 0, stream>>>(
            RTo, Ko, f_W, p_W, p_b, pred, t0, Tc);
    }
}

// Round 4
// 264.269 us; speedup vs baseline: 2.5145x; 1.5440x over previous
//
#include <hip/hip_runtime.h>
#include <math.h>

// Problem constants (fixed by setup_inputs)
#define BB 256      // batch
#define TT 256      // time steps
#define NQ 1000     // num_q
#define DK 128
#define DV 128
#define CC 32

typedef short s16x8 __attribute__((ext_vector_type(8)));   // 8 bf16 bit-patterns
typedef float f32x4 __attribute__((ext_vector_type(4)));

__device__ __forceinline__ float fast_sigmoid(float x) {
    x = fminf(fmaxf(x, -30.f), 30.f);
    return 1.f / (1.f + __expf(-x));
}
__device__ __forceinline__ float fast_tanh(float x) {
    x = fminf(fmaxf(x, -15.f), 15.f);
    float t = __expf(2.f * x);
    return (t - 1.f) / (t + 1.f);
}
__device__ __forceinline__ unsigned short f2bf(float f) {   // RNE fp32->bf16
    unsigned u = __float_as_uint(f);
    u += 0x7fffu + ((u >> 16) & 1u);
    return (unsigned short)(u >> 16);
}
__device__ __forceinline__ float bf2f(unsigned short h) {
    return __uint_as_float((unsigned)h << 16);
}

// ---------------------------------------------------------------------------
// conv_kernel: build bf16 TRANSPOSED weights in ws (B-operand layout Wt[n][k]):
//   eWt[d][j]=eW[j][d], aWt[d][j]=aW[j][d], fWat[d][j]=fW[j][d],
//   fWbt[d][j]=fW[128+j][d], Mkt[c][j]=Mk[j][c]
// ---------------------------------------------------------------------------
__global__ __launch_bounds__(256) void conv_kernel(
    const float* __restrict__ eW, const float* __restrict__ aW,
    const float* __restrict__ fW, const float* __restrict__ Mk,
    unsigned short* __restrict__ eWt, unsigned short* __restrict__ aWt,
    unsigned short* __restrict__ fWat, unsigned short* __restrict__ fWbt,
    unsigned short* __restrict__ Mkt)
{
    int idx = blockIdx.x * 256 + threadIdx.x;
    if (idx < 16384) {
        int n = idx >> 7, k = idx & 127;
        eWt[idx] = f2bf(eW[k * 128 + n]);
    } else if (idx < 32768) {
        int i = idx - 16384; int n = i >> 7, k = i & 127;
        aWt[i] = f2bf(aW[k * 128 + n]);
    } else if (idx < 49152) {
        int i = idx - 32768; int n = i >> 7, k = i & 127;
        fWat[i] = f2bf(fW[k * 128 + n]);
    } else if (idx < 65536) {
        int i = idx - 49152; int n = i >> 7, k = i & 127;
        fWbt[i] = f2bf(fW[(128 + k) * 128 + n]);
    } else if (idx < 69632) {
        int i = idx - 65536; int n = i >> 7, k = i & 127;   // n=c 0..31
        Mkt[i] = f2bf(Mk[k * 32 + n]);
    }
}

// ---------------------------------------------------------------------------
// MFMA helper: wave computes 16 rows x (NT*16) cols, K=128.
// A-frag: lane&15 = m, k = (lane>>4)*8 + j. B-frag (from Wt[n][k]):
// lane&15 = n, k = (lane>>4)*8 + j. D: col = lane&15, row = (lane>>4)*4 + reg.
// ---------------------------------------------------------------------------
template <int NT, class F>
__device__ __forceinline__ void mfma_phase(const unsigned short* Wlds,
                                           const s16x8 (&aF)[4], int lane, F emit)
{
    const int quad = lane >> 4, nrow = lane & 15;
#pragma unroll
    for (int nt = 0; nt < NT; ++nt) {
        f32x4 acc = {0.f, 0.f, 0.f, 0.f};
#pragma unroll
        for (int kb = 0; kb < 4; ++kb) {
            s16x8 bf = *(const s16x8*)&Wlds[(nt * 16 + nrow) * 136 + kb * 32 + quad * 8];
            acc = __builtin_amdgcn_mfma_f32_16x16x32_bf16(aF[kb], bf, acc, 0, 0, 0);
        }
        int col = nt * 16 + nrow;
        emit(quad * 4 + 0, col, acc[0]);
        emit(quad * 4 + 1, col, acc[1]);
        emit(quad * 4 + 2, col, acc[2]);
        emit(quad * 4 + 3, col, acc[3]);
    }
}

// ---------------------------------------------------------------------------
// pre_kernel (MFMA): block = 256 thr (4 waves) = 64 (b,t) rows.
//   Wo  fp32 [r][32]   = softmax(kt@Mk)
//   EA  u32  [r][128]  = packed bf16 (lo=et=sigmoid(vt@eW+eb), hi=at=tanh(vt@aW+ab))
//   Ko  bf16 [r][128]  = kt@fW[128:] + fb
// ---------------------------------------------------------------------------
__global__ __launch_bounds__(256) void pre_kernel(
    const int* __restrict__ skills, const int* __restrict__ responses,
    const float* __restrict__ k_emb, const float* __restrict__ v_emb,
    const float* __restrict__ fb, const float* __restrict__ eb,
    const float* __restrict__ ab,
    const unsigned short* __restrict__ Mkt, const unsigned short* __restrict__ fWbt,
    const unsigned short* __restrict__ eWt, const unsigned short* __restrict__ aWt,
    float* __restrict__ Wo, unsigned* __restrict__ EA,
    unsigned short* __restrict__ Ko, float* __restrict__ outTrue,
    int t0, int Tc)
{
    const int tid = threadIdx.x;
    const int lane = tid & 63;
    const int m_base = (tid >> 6) * 16;        // wave's row offset (0/16/32/48)
    const int mrow = lane & 15, quad = lane >> 4;
    const size_t base = (size_t)blockIdx.x * 64;

    __shared__ __align__(16) unsigned short Albs[64 * 136];
    __shared__ __align__(16) unsigned short Wlds[128 * 136];
    __shared__ float lg[64 * 33];
    __shared__ int sIdx[64], qIdx[64];

    // phase 0: indices + outTrue
    if (tid < 64) {
        int flat = (int)base + tid;
        int b = flat / Tc, tcc = flat % Tc;
        int t = t0 + tcc;
        int gi = b * TT + t;
        int s = skills[gi];
        int r = responses[gi];
        sIdx[tid] = s;
        qIdx[tid] = s + NQ * ((r > -1) ? r : 0);
        if (t >= 1) outTrue[b * (TT - 1) + (t - 1)] = (float)r;
    }
    __syncthreads();

    // phase 1: gather kt -> Albs (bf16), stage Mkt -> Wlds[0:32]
    {
        int row = tid >> 2, c0 = (tid & 3) * 32;
        int s = sIdx[row];
        const float* src = k_emb + (size_t)s * DK + c0;
#pragma unroll
        for (int j = 0; j < 8; ++j) {
            float4 v = *(const float4*)(src + j * 4);
            unsigned short* dp = &Albs[row * 136 + c0 + j * 4];
            dp[0] = f2bf(v.x); dp[1] = f2bf(v.y); dp[2] = f2bf(v.z); dp[3] = f2bf(v.w);
        }
        int n = tid >> 3, k0 = (tid & 7) * 16;
        *(s16x8*)&Wlds[n * 136 + k0]     = *(const s16x8*)&Mkt[n * 128 + k0];
        *(s16x8*)&Wlds[n * 136 + k0 + 8] = *(const s16x8*)&Mkt[n * 128 + k0 + 8];
    }
    __syncthreads();

    // phase 2: kt A-frags + logits MFMA -> lg
    s16x8 aF[4];
#pragma unroll
    for (int kb = 0; kb < 4; ++kb)
        aF[kb] = *(const s16x8*)&Albs[(m_base + mrow) * 136 + kb * 32 + quad * 8];
    mfma_phase<2>(Wlds, aF, lane, [&](int ml, int col, float x) {
        lg[(m_base + ml) * 33 + col] = x;
    });
    __syncthreads();

    // phase 3: stage fWbt -> Wlds; softmax (first 64 threads) -> Wo
    {
        int n = tid >> 1, k0 = (tid & 1) * 64;
#pragma unroll
        for (int j = 0; j < 8; ++j)
            *(s16x8*)&Wlds[n * 136 + k0 + j * 8] = *(const s16x8*)&fWbt[n * 128 + k0 + j * 8];
    }
    if (tid < 64) {
        float m = -1e30f;
#pragma unroll
        for (int c = 0; c < CC; ++c) m = fmaxf(m, lg[tid * 33 + c]);
        float ex[CC]; float sum = 0.f;
#pragma unroll
        for (int c = 0; c < CC; ++c) { ex[c] = __expf(lg[tid * 33 + c] - m); sum += ex[c]; }
        float inv = 1.f / sum;
        float* wp = Wo + (base + tid) * CC;
#pragma unroll
        for (int c = 0; c < CC; c += 4)
            *(float4*)(wp + c) = make_float4(ex[c] * inv, ex[c + 1] * inv,
                                             ex[c + 2] * inv, ex[c + 3] * inv);
    }
    __syncthreads();

    // phase 4: ck = kt@fWb + fb -> Ko (bf16)
    mfma_phase<8>(Wlds, aF, lane, [&](int ml, int col, float x) {
        size_t r = base + m_base + ml;
        Ko[r * 128 + col] = f2bf(x + fb[col]);
    });
    __syncthreads();

    // phase 5: gather vt -> Albs; stage eWt -> Wlds
    {
        int row = tid >> 2, c0 = (tid & 3) * 32;
        int q = qIdx[row];
        const float* src = v_emb + (size_t)q * DV + c0;
#pragma unroll
        for (int j = 0; j < 8; ++j) {
            float4 v = *(const float4*)(src + j * 4);
            unsigned short* dp = &Albs[row * 136 + c0 + j * 4];
            dp[0] = f2bf(v.x); dp[1] = f2bf(v.y); dp[2] = f2bf(v.z); dp[3] = f2bf(v.w);
        }
        int n = tid >> 1, k0 = (tid & 1) * 64;
#pragma unroll
        for (int j = 0; j < 8; ++j)
            *(s16x8*)&Wlds[n * 136 + k0 + j * 8] = *(const s16x8*)&eWt[n * 128 + k0 + j * 8];
    }
    __syncthreads();

    // phase 6: et = sigmoid(vt@eW + eb) -> EA low half
#pragma unroll
    for (int kb = 0; kb < 4; ++kb)
        aF[kb] = *(const s16x8*)&Albs[(m_base + mrow) * 136 + kb * 32 + quad * 8];
    mfma_phase<8>(Wlds, aF, lane, [&](int ml, int col, float x) {
        size_t r = base + m_base + ml;
        ((unsigned short*)EA)[(r * 128 + col) * 2] = f2bf(fast_sigmoid(x + eb[col]));
    });
    __syncthreads();

    // phase 7: stage aWt -> Wlds
    {
        int n = tid >> 1, k0 = (tid & 1) * 64;
#pragma unroll
        for (int j = 0; j < 8; ++j)
            *(s16x8*)&Wlds[n * 136 + k0 + j * 8] = *(const s16x8*)&aWt[n * 128 + k0 + j * 8];
    }
    __syncthreads();

    // phase 8: at = tanh(vt@aW + ab) -> EA high half
    mfma_phase<8>(Wlds, aF, lane, [&](int ml, int col, float x) {
        size_t r = base + m_base + ml;
        ((unsigned short*)EA)[(r * 128 + col) * 2 + 1] = f2bf(fast_tanh(x + ab[col]));
    });
}

// ---------------------------------------------------------------------------
// seq_kernel v4: 1 block/batch, 128 thr, thread d owns Mv[:,d] (32 regs).
// Zero barriers/LDS. 4-deep named-buffer pipeline (prefetch->use = 3 steps).
// EA packed bf16 pair = one 4B load/step; RT stored bf16.
// ---------------------------------------------------------------------------

struct Ops { float4 w[8]; float e, a; };

#define SEQ_LOAD(B, t) do {                                                   \
    int _tt = (t) < Tc ? (t) : (Tc - 1);                                      \
    _Pragma("unroll")                                                         \
    for (int q = 0; q < 8; ++q) B.w[q] = W4[(size_t)_tt * 8 + q];             \
    unsigned _ea = EAb[(size_t)_tt * 128];                                    \
    B.e = __uint_as_float(_ea << 16);                                         \
    B.a = __uint_as_float(_ea & 0xffff0000u);                                 \
} while (0)

#define SEQ_STEP(B, t) do {                                                   \
    float r0 = 0.f, r1 = 0.f, r2 = 0.f, r3 = 0.f;                             \
    _Pragma("unroll")                                                         \
    for (int q = 0; q < 8; ++q) {                                             \
        float4 w4 = B.w[q];                                                   \
        r0 = fmaf(w4.x, Mv[4*q+0], r0);                                       \
        r1 = fmaf(w4.y, Mv[4*q+1], r1);                                       \
        r2 = fmaf(w4.z, Mv[4*q+2], r2);                                       \
        r3 = fmaf(w4.w, Mv[4*q+3], r3);                                       \
    }                                                                         \
    RTb[(size_t)(t) * 128] = f2bf((r0 + r1) + (r2 + r3));                     \
    const float _e = B.e, _a = B.a;                                           \
    _Pragma("unroll")                                                         \
    for (int q = 0; q < 8; ++q) {                                             \
        float4 w4 = B.w[q];                                                   \
        Mv[4*q+0] = fmaf(w4.x, fmaf(-_e, Mv[4*q+0], _a), Mv[4*q+0]);          \
        Mv[4*q+1] = fmaf(w4.y, fmaf(-_e, Mv[4*q+1], _a), Mv[4*q+1]);          \
        Mv[4*q+2] = fmaf(w4.z, fmaf(-_e, Mv[4*q+2], _a), Mv[4*q+2]);          \
        Mv[4*q+3] = fmaf(w4.w, fmaf(-_e, Mv[4*q+3], _a), Mv[4*q+3]);          \
    }                                                                         \
} while (0)

__global__ __launch_bounds__(128, 1) void seq_kernel(
    const float* __restrict__ W, const unsigned* __restrict__ EA,
    const float* __restrict__ Mv0,
    unsigned short* __restrict__ RT, float* __restrict__ MvWS,
    int Tc, int doInit, int doSave)
{
    const int b = blockIdx.x;
    const int d = threadIdx.x;

    float Mv[32];
    if (doInit) {
#pragma unroll
        for (int c = 0; c < 32; ++c) Mv[c] = Mv0[c * 128 + d];
    } else {
#pragma unroll
        for (int c = 0; c < 32; ++c) Mv[c] = MvWS[(size_t)b * 4096 + c * 128 + d];
    }

    const float4* __restrict__ W4 = (const float4*)(W + (size_t)b * Tc * CC);
    const unsigned* __restrict__ EAb = EA + (size_t)b * Tc * 128 + d;
    unsigned short* __restrict__ RTb = RT + (size_t)b * Tc * 128 + d;

    Ops B0, B1, B2, B3;
    SEQ_LOAD(B0, 0); SEQ_LOAD(B1, 1); SEQ_LOAD(B2, 2); SEQ_LOAD(B3, 3);

    for (int tc = 0; tc < Tc; tc += 4) {   // Tc is a multiple of 4
        SEQ_STEP(B0, tc);     SEQ_LOAD(B0, tc + 4);
        SEQ_STEP(B1, tc + 1); SEQ_LOAD(B1, tc + 5);
        SEQ_STEP(B2, tc + 2); SEQ_LOAD(B2, tc + 6);
        SEQ_STEP(B3, tc + 3); SEQ_LOAD(B3, tc + 7);
    }

    if (doSave) {
#pragma unroll
        for (int c = 0; c < 32; ++c) MvWS[(size_t)b * 4096 + c * 128 + d] = Mv[c];
    }
}

// ---------------------------------------------------------------------------
// post_kernel (MFMA): ft = tanh(rt@fWa + ck), pt = sigmoid(ft.pW + pb).
// Block = 256 thr (4 waves) = 64 rows. Per-lane partial dot over cols, then
// 16-lane shuffle reduce; rows quad*4+reg written by lane&15==0.
// ---------------------------------------------------------------------------
__global__ __launch_bounds__(256) void post_kernel(
    const unsigned short* __restrict__ RT, const unsigned short* __restrict__ Ko,
    const unsigned short* __restrict__ fWat, const float* __restrict__ pW,
    const float* __restrict__ pb,
    float* __restrict__ pred, int t0, int Tc)
{
    const int tid = threadIdx.x;
    const int lane = tid & 63;
    const int m_base = (tid >> 6) * 16;
    const int mrow = lane & 15, quad = lane >> 4;
    const size_t base = (size_t)blockIdx.x * 64;

    __shared__ __align__(16) unsigned short Albs[64 * 136];
    __shared__ __align__(16) unsigned short Wlds[128 * 136];

    // stage rt (bf16, contiguous) + fWat
    {
        int row = tid >> 2, c0 = (tid & 3) * 32;
#pragma unroll
        for (int j = 0; j < 4; ++j)
            *(s16x8*)&Albs[row * 136 + c0 + j * 8] =
                *(const s16x8*)&RT[(base + row) * 128 + c0 + j * 8];
        int n = tid >> 1, k0 = (tid & 1) * 64;
#pragma unroll
        for (int j = 0; j < 8; ++j)
            *(s16x8*)&Wlds[n * 136 + k0 + j * 8] = *(const s16x8*)&fWat[n * 128 + k0 + j * 8];
    }
    __syncthreads();

    s16x8 aF[4];
#pragma unroll
    for (int kb = 0; kb < 4; ++kb)
        aF[kb] = *(const s16x8*)&Albs[(m_base + mrow) * 136 + kb * 32 + quad * 8];

    float p0 = 0.f, p1 = 0.f, p2 = 0.f, p3 = 0.f;
#pragma unroll
    for (int nt = 0; nt < 8; ++nt) {
        f32x4 acc = {0.f, 0.f, 0.f, 0.f};
#pragma unroll
        for (int kb = 0; kb < 4; ++kb) {
            s16x8 bf = *(const s16x8*)&Wlds[(nt * 16 + mrow) * 136 + kb * 32 + quad * 8];
            acc = __builtin_amdgcn_mfma_f32_16x16x32_bf16(aF[kb], bf, acc, 0, 0, 0);
        }
        int col = nt * 16 + mrow;
        float pw = pW[col];
        size_t rbase = base + m_base + quad * 4;
        p0 = fmaf(fast_tanh(acc[0] + bf2f(Ko[(rbase + 0) * 128 + col])), pw, p0);
        p1 = fmaf(fast_tanh(acc[1] + bf2f(Ko[(rbase + 1) * 128 + col])), pw, p1);
        p2 = fmaf(fast_tanh(acc[2] + bf2f(Ko[(rbase + 2) * 128 + col])), pw, p2);
        p3 = fmaf(fast_tanh(acc[3] + bf2f(Ko[(rbase + 3) * 128 + col])), pw, p3);
    }
#pragma unroll
    for (int off = 1; off < 16; off <<= 1) {
        p0 += __shfl_xor(p0, off, 64);
        p1 += __shfl_xor(p1, off, 64);
        p2 += __shfl_xor(p2, off, 64);
        p3 += __shfl_xor(p3, off, 64);
    }

    if (mrow == 0) {
        float pbv = pb[0];
        float ps[4] = {p0, p1, p2, p3};
#pragma unroll
        for (int reg = 0; reg < 4; ++reg) {
            int r = (int)base + m_base + quad * 4 + reg;
            int b = r / Tc, tcc = r % Tc;
            int t = t0 + tcc;
            if (t < TT - 1)
                pred[b * (TT - 1) + t] = fast_sigmoid(ps[reg] + pbv);
        }
    }
}

// ---------------------------------------------------------------------------

extern "C" void kernel_launch(void* const* d_in, const int* in_sizes, int n_in,
                              void* d_out, int out_size, void* d_ws, size_t ws_size,
                              hipStream_t stream) {
    const int*   skills    = (const int*)d_in[0];
    const int*   responses = (const int*)d_in[1];
    const float* k_emb     = (const float*)d_in[2];
    const float* v_emb     = (const float*)d_in[3];
    const float* Mk        = (const float*)d_in[4];
    const float* Mv0       = (const float*)d_in[5];
    const float* f_W       = (const float*)d_in[6];
    const float* f_b       = (const float*)d_in[7];
    const float* p_W       = (const float*)d_in[8];
    const float* p_b       = (const float*)d_in[9];
    const float* e_W       = (const float*)d_in[10];
    const float* e_b       = (const float*)d_in[11];
    const float* a_W       = (const float*)d_in[12];
    const float* a_b       = (const float*)d_in[13];

    float* pred    = (float*)d_out;                 // [256][255]
    float* outTrue = pred + BB * (TT - 1);          // [256][255]

    // scratch: Wo fp32 + EA u32 + Ko bf16 + RT bf16 (per row: 128+512+256+256 B)
    int Tc = TT;
    for (;;) {
        size_t need = (size_t)BB * Tc * 1152 + 69632 * 2;
        if (Tc < TT) need += (size_t)BB * 4096 * 4;
        if (need <= ws_size || Tc <= 32) break;
        Tc >>= 1;
    }

    char* p = (char*)d_ws;
    float* Wo = (float*)p;                 p += (size_t)BB * Tc * 32 * 4;
    unsigned* EA = (unsigned*)p;           p += (size_t)BB * Tc * 128 * 4;
    unsigned short* Ko = (unsigned short*)p;   p += (size_t)BB * Tc * 128 * 2;
    unsigned short* RT = (unsigned short*)p;   p += (size_t)BB * Tc * 128 * 2;
    unsigned short* eWt = (unsigned short*)p;  p += 16384 * 2;
    unsigned short* aWt = (unsigned short*)p;  p += 16384 * 2;
    unsigned short* fWat = (unsigned short*)p; p += 16384 * 2;
    unsigned short* fWbt = (unsigned short*)p; p += 16384 * 2;
    unsigned short* Mkt = (unsigned short*)p;  p += 4096 * 2;
    float* MvWS = (float*)p;

    conv_kernel<<<272, 256, 0, stream>>>(e_W, a_W, f_W, Mk,
                                         eWt, aWt, fWat, fWbt, Mkt);

    for (int t0 = 0; t0 < TT; t0 += Tc) {
        pre_kernel<<<(BB * Tc) / 64, 256, 0, stream>>>(
            skills, responses, k_emb, v_emb, f_b, e_b, a_b,
            Mkt, fWbt, eWt, aWt, Wo, EA, Ko, outTrue, t0, Tc);
        seq_kernel<<<BB, 128, 0, stream>>>(
            Wo, EA, Mv0, RT, MvWS,
            Tc, t0 == 0 ? 1 : 0, (t0 + Tc < TT) ? 1 : 0);
        post_kernel<<<(BB * Tc) / 64, 256, 0, stream>>>(
            RT, Ko, fWat, p_W, p_b, pred, t0, Tc);
    }
}

// Round 5
// 219.981 us; speedup vs baseline: 3.0208x; 1.2013x over previous
//
#include <hip/hip_runtime.h>
#include <math.h>

// Problem constants (fixed by setup_inputs)
#define BB 256      // batch
#define TT 256      // time steps
#define NQ 1000     // num_q
#define DK 128
#define DV 128
#define CC 32

typedef short s16x8 __attribute__((ext_vector_type(8)));   // 8 bf16 bit-patterns
typedef float f32x4 __attribute__((ext_vector_type(4)));

__device__ __forceinline__ float fast_sigmoid(float x) {
    x = fminf(fmaxf(x, -30.f), 30.f);
    return 1.f / (1.f + __expf(-x));
}
__device__ __forceinline__ float fast_tanh(float x) {
    x = fminf(fmaxf(x, -15.f), 15.f);
    float t = __expf(2.f * x);
    return (t - 1.f) / (t + 1.f);
}
__device__ __forceinline__ unsigned short f2bf(float f) {   // RNE fp32->bf16
    unsigned u = __float_as_uint(f);
    u += 0x7fffu + ((u >> 16) & 1u);
    return (unsigned short)(u >> 16);
}
__device__ __forceinline__ float bf2f(unsigned short h) {
    return __uint_as_float((unsigned)h << 16);
}

// ---------------------------------------------------------------------------
// conv_kernel: build bf16 TRANSPOSED weights in ws (B-operand layout Wt[n][k])
// ---------------------------------------------------------------------------
__global__ __launch_bounds__(256) void conv_kernel(
    const float* __restrict__ eW, const float* __restrict__ aW,
    const float* __restrict__ fW, const float* __restrict__ Mk,
    unsigned short* __restrict__ eWt, unsigned short* __restrict__ aWt,
    unsigned short* __restrict__ fWat, unsigned short* __restrict__ fWbt,
    unsigned short* __restrict__ Mkt)
{
    int idx = blockIdx.x * 256 + threadIdx.x;
    if (idx < 16384) {
        int n = idx >> 7, k = idx & 127;
        eWt[idx] = f2bf(eW[k * 128 + n]);
    } else if (idx < 32768) {
        int i = idx - 16384; int n = i >> 7, k = i & 127;
        aWt[i] = f2bf(aW[k * 128 + n]);
    } else if (idx < 49152) {
        int i = idx - 32768; int n = i >> 7, k = i & 127;
        fWat[i] = f2bf(fW[k * 128 + n]);
    } else if (idx < 65536) {
        int i = idx - 49152; int n = i >> 7, k = i & 127;
        fWbt[i] = f2bf(fW[(128 + k) * 128 + n]);
    } else if (idx < 69632) {
        int i = idx - 65536; int n = i >> 7, k = i & 127;   // n=c 0..31
        Mkt[i] = f2bf(Mk[k * 32 + n]);
    }
}

// ---------------------------------------------------------------------------
// MFMA helper (unchanged): wave computes 16 rows x (NT*16) cols, K=128.
// ---------------------------------------------------------------------------
template <int NT, class F>
__device__ __forceinline__ void mfma_phase(const unsigned short* Wlds,
                                           const s16x8 (&aF)[4], int lane, F emit)
{
    const int quad = lane >> 4, nrow = lane & 15;
#pragma unroll
    for (int nt = 0; nt < NT; ++nt) {
        f32x4 acc = {0.f, 0.f, 0.f, 0.f};
#pragma unroll
        for (int kb = 0; kb < 4; ++kb) {
            s16x8 bf = *(const s16x8*)&Wlds[(nt * 16 + nrow) * 136 + kb * 32 + quad * 8];
            acc = __builtin_amdgcn_mfma_f32_16x16x32_bf16(aF[kb], bf, acc, 0, 0, 0);
        }
        int col = nt * 16 + nrow;
        emit(quad * 4 + 0, col, acc[0]);
        emit(quad * 4 + 1, col, acc[1]);
        emit(quad * 4 + 2, col, acc[2]);
        emit(quad * 4 + 3, col, acc[3]);
    }
}

// ---------------------------------------------------------------------------
// pre_kernel (MFMA, unchanged from R4)
// ---------------------------------------------------------------------------
__global__ __launch_bounds__(256) void pre_kernel(
    const int* __restrict__ skills, const int* __restrict__ responses,
    const float* __restrict__ k_emb, const float* __restrict__ v_emb,
    const float* __restrict__ fb, const float* __restrict__ eb,
    const float* __restrict__ ab,
    const unsigned short* __restrict__ Mkt, const unsigned short* __restrict__ fWbt,
    const unsigned short* __restrict__ eWt, const unsigned short* __restrict__ aWt,
    float* __restrict__ Wo, unsigned* __restrict__ EA,
    unsigned short* __restrict__ Ko, float* __restrict__ outTrue,
    int t0, int Tc)
{
    const int tid = threadIdx.x;
    const int lane = tid & 63;
    const int m_base = (tid >> 6) * 16;
    const int mrow = lane & 15, quad = lane >> 4;
    const size_t base = (size_t)blockIdx.x * 64;

    __shared__ __align__(16) unsigned short Albs[64 * 136];
    __shared__ __align__(16) unsigned short Wlds[128 * 136];
    __shared__ float lg[64 * 33];
    __shared__ int sIdx[64], qIdx[64];

    if (tid < 64) {
        int flat = (int)base + tid;
        int b = flat / Tc, tcc = flat % Tc;
        int t = t0 + tcc;
        int gi = b * TT + t;
        int s = skills[gi];
        int r = responses[gi];
        sIdx[tid] = s;
        qIdx[tid] = s + NQ * ((r > -1) ? r : 0);
        if (t >= 1) outTrue[b * (TT - 1) + (t - 1)] = (float)r;
    }
    __syncthreads();

    {
        int row = tid >> 2, c0 = (tid & 3) * 32;
        int s = sIdx[row];
        const float* src = k_emb + (size_t)s * DK + c0;
#pragma unroll
        for (int j = 0; j < 8; ++j) {
            float4 v = *(const float4*)(src + j * 4);
            unsigned short* dp = &Albs[row * 136 + c0 + j * 4];
            dp[0] = f2bf(v.x); dp[1] = f2bf(v.y); dp[2] = f2bf(v.z); dp[3] = f2bf(v.w);
        }
        int n = tid >> 3, k0 = (tid & 7) * 16;
        *(s16x8*)&Wlds[n * 136 + k0]     = *(const s16x8*)&Mkt[n * 128 + k0];
        *(s16x8*)&Wlds[n * 136 + k0 + 8] = *(const s16x8*)&Mkt[n * 128 + k0 + 8];
    }
    __syncthreads();

    s16x8 aF[4];
#pragma unroll
    for (int kb = 0; kb < 4; ++kb)
        aF[kb] = *(const s16x8*)&Albs[(m_base + mrow) * 136 + kb * 32 + quad * 8];
    mfma_phase<2>(Wlds, aF, lane, [&](int ml, int col, float x) {
        lg[(m_base + ml) * 33 + col] = x;
    });
    __syncthreads();

    {
        int n = tid >> 1, k0 = (tid & 1) * 64;
#pragma unroll
        for (int j = 0; j < 8; ++j)
            *(s16x8*)&Wlds[n * 136 + k0 + j * 8] = *(const s16x8*)&fWbt[n * 128 + k0 + j * 8];
    }
    if (tid < 64) {
        float m = -1e30f;
#pragma unroll
        for (int c = 0; c < CC; ++c) m = fmaxf(m, lg[tid * 33 + c]);
        float ex[CC]; float sum = 0.f;
#pragma unroll
        for (int c = 0; c < CC; ++c) { ex[c] = __expf(lg[tid * 33 + c] - m); sum += ex[c]; }
        float inv = 1.f / sum;
        float* wp = Wo + (base + tid) * CC;
#pragma unroll
        for (int c = 0; c < CC; c += 4)
            *(float4*)(wp + c) = make_float4(ex[c] * inv, ex[c + 1] * inv,
                                             ex[c + 2] * inv, ex[c + 3] * inv);
    }
    __syncthreads();

    mfma_phase<8>(Wlds, aF, lane, [&](int ml, int col, float x) {
        size_t r = base + m_base + ml;
        Ko[r * 128 + col] = f2bf(x + fb[col]);
    });
    __syncthreads();

    {
        int row = tid >> 2, c0 = (tid & 3) * 32;
        int q = qIdx[row];
        const float* src = v_emb + (size_t)q * DV + c0;
#pragma unroll
        for (int j = 0; j < 8; ++j) {
            float4 v = *(const float4*)(src + j * 4);
            unsigned short* dp = &Albs[row * 136 + c0 + j * 4];
            dp[0] = f2bf(v.x); dp[1] = f2bf(v.y); dp[2] = f2bf(v.z); dp[3] = f2bf(v.w);
        }
        int n = tid >> 1, k0 = (tid & 1) * 64;
#pragma unroll
        for (int j = 0; j < 8; ++j)
            *(s16x8*)&Wlds[n * 136 + k0 + j * 8] = *(const s16x8*)&eWt[n * 128 + k0 + j * 8];
    }
    __syncthreads();

#pragma unroll
    for (int kb = 0; kb < 4; ++kb)
        aF[kb] = *(const s16x8*)&Albs[(m_base + mrow) * 136 + kb * 32 + quad * 8];
    mfma_phase<8>(Wlds, aF, lane, [&](int ml, int col, float x) {
        size_t r = base + m_base + ml;
        ((unsigned short*)EA)[(r * 128 + col) * 2] = f2bf(fast_sigmoid(x + eb[col]));
    });
    __syncthreads();

    {
        int n = tid >> 1, k0 = (tid & 1) * 64;
#pragma unroll
        for (int j = 0; j < 8; ++j)
            *(s16x8*)&Wlds[n * 136 + k0 + j * 8] = *(const s16x8*)&aWt[n * 128 + k0 + j * 8];
    }
    __syncthreads();

    mfma_phase<8>(Wlds, aF, lane, [&](int ml, int col, float x) {
        size_t r = base + m_base + ml;
        ((unsigned short*)EA)[(r * 128 + col) * 2 + 1] = f2bf(fast_tanh(x + ab[col]));
    });
}

// ---------------------------------------------------------------------------
// seq_kernel v5: 1 block/batch, 128 thr, thread d owns Mv[:,d] (32 regs).
//
// R2/R4 lesson: register-resident software pipelines get collapsed by the
// compiler (R4 VGPR_Count=64 -> load-to-use distance ~0 -> 1220 cyc/step of
// raw L3/HBM latency). v5 makes operands LDS-RESIDENT: double-buffered
// 32-step chunks (W fp32 + EA packed-bf16). Per chunk: ds_write the
// already-arrived chunk g+1, issue chunk g+2 global loads (a whole chunk's
// compute ahead of their barrier drain), compute 32 steps from LDS (ds_read
// latency ~120 cyc, broadcast w reads, 2-way EA reads = conflict-free).
// ---------------------------------------------------------------------------

#define CH 32
#define WROW 36     // Wl row stride (floats): 144 B, 16B-aligned rows
#define EROW 132    // EAl row stride (u32):   528 B, 16B-aligned rows

__global__ __launch_bounds__(128, 1) void seq_kernel(
    const float* __restrict__ W, const unsigned* __restrict__ EA,
    const float* __restrict__ Mv0,
    unsigned short* __restrict__ RT, float* __restrict__ MvWS,
    int Tc, int doInit, int doSave)
{
    const int b = blockIdx.x;
    const int tid = threadIdx.x;
    const int d = tid;

    __shared__ __align__(16) float    Wl[2][CH * WROW];
    __shared__ __align__(16) unsigned EAl[2][CH * EROW];

    float Mv[32];
    if (doInit) {
#pragma unroll
        for (int c = 0; c < 32; ++c) Mv[c] = Mv0[c * 128 + d];
    } else {
#pragma unroll
        for (int c = 0; c < 32; ++c) Mv[c] = MvWS[(size_t)b * 4096 + c * 128 + d];
    }

    const float* __restrict__ Wb = W + (size_t)b * Tc * 32;
    const unsigned* __restrict__ EAb = EA + (size_t)b * Tc * 128;
    unsigned short* __restrict__ RTb = RT + (size_t)b * Tc * 128 + d;

    const int lr = tid >> 2;            // load-mapping row within chunk (0..31)
    const int lq = tid & 3;             // col quarter (0..3)
    const int nch = Tc / CH;

    float4 wr0, wr1;                    // staged W slice (8 floats)
    uint4  er[8];                       // staged EA slice (32 u32)

    // ---- prologue: chunk 0 -> LDS buf0; issue chunk 1 loads ----
    {
        const float* ws = Wb;
        wr0 = *(const float4*)(ws + tid * 8);
        wr1 = *(const float4*)(ws + tid * 8 + 4);
        const unsigned* es = EAb + lr * 128 + lq * 32;
#pragma unroll
        for (int j = 0; j < 8; ++j) er[j] = *(const uint4*)(es + j * 4);

        float* wd = &Wl[0][lr * WROW + lq * 8];
        *(float4*)wd = wr0; *(float4*)(wd + 4) = wr1;
        unsigned* ed = &EAl[0][lr * EROW + lq * 32];
#pragma unroll
        for (int j = 0; j < 8; ++j) *(uint4*)(ed + j * 4) = er[j];
    }
    if (nch > 1) {
        const float* ws = Wb + CH * 32;
        wr0 = *(const float4*)(ws + tid * 8);
        wr1 = *(const float4*)(ws + tid * 8 + 4);
        const unsigned* es = EAb + CH * 128 + lr * 128 + lq * 32;
#pragma unroll
        for (int j = 0; j < 8; ++j) er[j] = *(const uint4*)(es + j * 4);
    }
    __syncthreads();

    for (int g = 0; g < nch; ++g) {
        const int cur = g & 1;

        // publish chunk g+1 (regs arrived >= 1 full chunk ago)
        if (g + 1 < nch) {
            float* wd = &Wl[cur ^ 1][lr * WROW + lq * 8];
            *(float4*)wd = wr0; *(float4*)(wd + 4) = wr1;
            unsigned* ed = &EAl[cur ^ 1][lr * EROW + lq * 32];
#pragma unroll
            for (int j = 0; j < 8; ++j) *(uint4*)(ed + j * 4) = er[j];
        }
        // issue chunk g+2 loads (drain at end-of-chunk barrier, ~6400 cyc away)
        if (g + 2 < nch) {
            const float* ws = Wb + (size_t)(g + 2) * CH * 32;
            wr0 = *(const float4*)(ws + tid * 8);
            wr1 = *(const float4*)(ws + tid * 8 + 4);
            const unsigned* es = EAb + ((size_t)(g + 2) * CH + lr) * 128 + lq * 32;
#pragma unroll
            for (int j = 0; j < 8; ++j) er[j] = *(const uint4*)(es + j * 4);
        }

        const float* wlc = Wl[cur];
        const unsigned* elc = EAl[cur];

#pragma unroll 4
        for (int tl = 0; tl < CH; ++tl) {
            const float* wrow = wlc + tl * WROW;
            float4 wv[8];
#pragma unroll
            for (int q = 0; q < 8; ++q) wv[q] = *(const float4*)(wrow + q * 4);
            unsigned ea = elc[tl * EROW + d];
            float e = __uint_as_float(ea << 16);
            float a = __uint_as_float(ea & 0xffff0000u);

            float r0 = 0.f, r1 = 0.f, r2 = 0.f, r3 = 0.f;
#pragma unroll
            for (int q = 0; q < 8; ++q) {
                r0 = fmaf(wv[q].x, Mv[4*q+0], r0);
                r1 = fmaf(wv[q].y, Mv[4*q+1], r1);
                r2 = fmaf(wv[q].z, Mv[4*q+2], r2);
                r3 = fmaf(wv[q].w, Mv[4*q+3], r3);
            }
            RTb[(size_t)(g * CH + tl) * 128] = f2bf((r0 + r1) + (r2 + r3));

#pragma unroll
            for (int q = 0; q < 8; ++q) {
                Mv[4*q+0] = fmaf(wv[q].x, fmaf(-e, Mv[4*q+0], a), Mv[4*q+0]);
                Mv[4*q+1] = fmaf(wv[q].y, fmaf(-e, Mv[4*q+1], a), Mv[4*q+1]);
                Mv[4*q+2] = fmaf(wv[q].z, fmaf(-e, Mv[4*q+2], a), Mv[4*q+2]);
                Mv[4*q+3] = fmaf(wv[q].w, fmaf(-e, Mv[4*q+3], a), Mv[4*q+3]);
            }
        }
        __syncthreads();
    }

    if (doSave) {
#pragma unroll
        for (int c = 0; c < 32; ++c) MvWS[(size_t)b * 4096 + c * 128 + d] = Mv[c];
    }
}

// ---------------------------------------------------------------------------
// post_kernel (MFMA, unchanged from R4)
// ---------------------------------------------------------------------------
__global__ __launch_bounds__(256) void post_kernel(
    const unsigned short* __restrict__ RT, const unsigned short* __restrict__ Ko,
    const unsigned short* __restrict__ fWat, const float* __restrict__ pW,
    const float* __restrict__ pb,
    float* __restrict__ pred, int t0, int Tc)
{
    const int tid = threadIdx.x;
    const int lane = tid & 63;
    const int m_base = (tid >> 6) * 16;
    const int mrow = lane & 15, quad = lane >> 4;
    const size_t base = (size_t)blockIdx.x * 64;

    __shared__ __align__(16) unsigned short Albs[64 * 136];
    __shared__ __align__(16) unsigned short Wlds[128 * 136];

    {
        int row = tid >> 2, c0 = (tid & 3) * 32;
#pragma unroll
        for (int j = 0; j < 4; ++j)
            *(s16x8*)&Albs[row * 136 + c0 + j * 8] =
                *(const s16x8*)&RT[(base + row) * 128 + c0 + j * 8];
        int n = tid >> 1, k0 = (tid & 1) * 64;
#pragma unroll
        for (int j = 0; j < 8; ++j)
            *(s16x8*)&Wlds[n * 136 + k0 + j * 8] = *(const s16x8*)&fWat[n * 128 + k0 + j * 8];
    }
    __syncthreads();

    s16x8 aF[4];
#pragma unroll
    for (int kb = 0; kb < 4; ++kb)
        aF[kb] = *(const s16x8*)&Albs[(m_base + mrow) * 136 + kb * 32 + quad * 8];

    float p0 = 0.f, p1 = 0.f, p2 = 0.f, p3 = 0.f;
#pragma unroll
    for (int nt = 0; nt < 8; ++nt) {
        f32x4 acc = {0.f, 0.f, 0.f, 0.f};
#pragma unroll
        for (int kb = 0; kb < 4; ++kb) {
            s16x8 bf = *(const s16x8*)&Wlds[(nt * 16 + mrow) * 136 + kb * 32 + quad * 8];
            acc = __builtin_amdgcn_mfma_f32_16x16x32_bf16(aF[kb], bf, acc, 0, 0, 0);
        }
        int col = nt * 16 + mrow;
        float pw = pW[col];
        size_t rbase = base + m_base + quad * 4;
        p0 = fmaf(fast_tanh(acc[0] + bf2f(Ko[(rbase + 0) * 128 + col])), pw, p0);
        p1 = fmaf(fast_tanh(acc[1] + bf2f(Ko[(rbase + 1) * 128 + col])), pw, p1);
        p2 = fmaf(fast_tanh(acc[2] + bf2f(Ko[(rbase + 2) * 128 + col])), pw, p2);
        p3 = fmaf(fast_tanh(acc[3] + bf2f(Ko[(rbase + 3) * 128 + col])), pw, p3);
    }
#pragma unroll
    for (int off = 1; off < 16; off <<= 1) {
        p0 += __shfl_xor(p0, off, 64);
        p1 += __shfl_xor(p1, off, 64);
        p2 += __shfl_xor(p2, off, 64);
        p3 += __shfl_xor(p3, off, 64);
    }

    if (mrow == 0) {
        float pbv = pb[0];
        float ps[4] = {p0, p1, p2, p3};
#pragma unroll
        for (int reg = 0; reg < 4; ++reg) {
            int r = (int)base + m_base + quad * 4 + reg;
            int b = r / Tc, tcc = r % Tc;
            int t = t0 + tcc;
            if (t < TT - 1)
                pred[b * (TT - 1) + t] = fast_sigmoid(ps[reg] + pbv);
        }
    }
}

// ---------------------------------------------------------------------------

extern "C" void kernel_launch(void* const* d_in, const int* in_sizes, int n_in,
                              void* d_out, int out_size, void* d_ws, size_t ws_size,
                              hipStream_t stream) {
    const int*   skills    = (const int*)d_in[0];
    const int*   responses = (const int*)d_in[1];
    const float* k_emb     = (const float*)d_in[2];
    const float* v_emb     = (const float*)d_in[3];
    const float* Mk        = (const float*)d_in[4];
    const float* Mv0       = (const float*)d_in[5];
    const float* f_W       = (const float*)d_in[6];
    const float* f_b       = (const float*)d_in[7];
    const float* p_W       = (const float*)d_in[8];
    const float* p_b       = (const float*)d_in[9];
    const float* e_W       = (const float*)d_in[10];
    const float* e_b       = (const float*)d_in[11];
    const float* a_W       = (const float*)d_in[12];
    const float* a_b       = (const float*)d_in[13];

    float* pred    = (float*)d_out;                 // [256][255]
    float* outTrue = pred + BB * (TT - 1);          // [256][255]

    // scratch: Wo fp32 + EA u32 + Ko bf16 + RT bf16 (per row: 128+512+256+256 B)
    int Tc = TT;
    for (;;) {
        size_t need = (size_t)BB * Tc * 1152 + 69632 * 2;
        if (Tc < TT) need += (size_t)BB * 4096 * 4;
        if (need <= ws_size || Tc <= 32) break;
        Tc >>= 1;
    }

    char* p = (char*)d_ws;
    float* Wo = (float*)p;                 p += (size_t)BB * Tc * 32 * 4;
    unsigned* EA = (unsigned*)p;           p += (size_t)BB * Tc * 128 * 4;
    unsigned short* Ko = (unsigned short*)p;   p += (size_t)BB * Tc * 128 * 2;
    unsigned short* RT = (unsigned short*)p;   p += (size_t)BB * Tc * 128 * 2;
    unsigned short* eWt = (unsigned short*)p;  p += 16384 * 2;
    unsigned short* aWt = (unsigned short*)p;  p += 16384 * 2;
    unsigned short* fWat = (unsigned short*)p; p += 16384 * 2;
    unsigned short* fWbt = (unsigned short*)p; p += 16384 * 2;
    unsigned short* Mkt = (unsigned short*)p;  p += 4096 * 2;
    float* MvWS = (float*)p;

    conv_kernel<<<272, 256, 0, stream>>>(e_W, a_W, f_W, Mk,
                                         eWt, aWt, fWat, fWbt, Mkt);

    for (int t0 = 0; t0 < TT; t0 += Tc) {
        pre_kernel<<<(BB * Tc) / 64, 256, 0, stream>>>(
            skills, responses, k_emb, v_emb, f_b, e_b, a_b,
            Mkt, fWbt, eWt, aWt, Wo, EA, Ko, outTrue, t0, Tc);
        seq_kernel<<<BB, 128, 0, stream>>>(
            Wo, EA, Mv0, RT, MvWS,
            Tc, t0 == 0 ? 1 : 0, (t0 + Tc < TT) ? 1 : 0);
        post_kernel<<<(BB * Tc) / 64, 256, 0, stream>>>(
            RT, Ko, fWat, p_W, p_b, pred, t0, Tc);
    }
}

// Round 6
// 203.069 us; speedup vs baseline: 3.2724x; 1.0833x over previous
//
#include <hip/hip_runtime.h>
#include <math.h>

// Problem constants (fixed by setup_inputs)
#define BB 256      // batch
#define TT 256      // time steps
#define NQ 1000     // num_q
#define DK 128
#define DV 128
#define CC 32

typedef short s16x8 __attribute__((ext_vector_type(8)));   // 8 bf16 bit-patterns
typedef float f32x4 __attribute__((ext_vector_type(4)));

__device__ __forceinline__ float fast_sigmoid(float x) {
    x = fminf(fmaxf(x, -30.f), 30.f);
    return 1.f / (1.f + __expf(-x));
}
__device__ __forceinline__ float fast_tanh(float x) {
    x = fminf(fmaxf(x, -15.f), 15.f);
    float t = __expf(2.f * x);
    return (t - 1.f) / (t + 1.f);
}
__device__ __forceinline__ unsigned short f2bf(float f) {   // RNE fp32->bf16
    unsigned u = __float_as_uint(f);
    u += 0x7fffu + ((u >> 16) & 1u);
    return (unsigned short)(u >> 16);
}
__device__ __forceinline__ float bf2f(unsigned short h) {
    return __uint_as_float((unsigned)h << 16);
}
__device__ __forceinline__ unsigned u4get(uint4 v, int i) { // i constant after unroll
    return i == 0 ? v.x : i == 1 ? v.y : i == 2 ? v.z : v.w;
}

// ---------------------------------------------------------------------------
// conv_kernel: build bf16 TRANSPOSED weights in ws (B-operand layout Wt[n][k])
// ---------------------------------------------------------------------------
__global__ __launch_bounds__(256) void conv_kernel(
    const float* __restrict__ eW, const float* __restrict__ aW,
    const float* __restrict__ fW, const float* __restrict__ Mk,
    unsigned short* __restrict__ eWt, unsigned short* __restrict__ aWt,
    unsigned short* __restrict__ fWat, unsigned short* __restrict__ fWbt,
    unsigned short* __restrict__ Mkt)
{
    int idx = blockIdx.x * 256 + threadIdx.x;
    if (idx < 16384) {
        int n = idx >> 7, k = idx & 127;
        eWt[idx] = f2bf(eW[k * 128 + n]);
    } else if (idx < 32768) {
        int i = idx - 16384; int n = i >> 7, k = i & 127;
        aWt[i] = f2bf(aW[k * 128 + n]);
    } else if (idx < 49152) {
        int i = idx - 32768; int n = i >> 7, k = i & 127;
        fWat[i] = f2bf(fW[k * 128 + n]);
    } else if (idx < 65536) {
        int i = idx - 49152; int n = i >> 7, k = i & 127;
        fWbt[i] = f2bf(fW[(128 + k) * 128 + n]);
    } else if (idx < 69632) {
        int i = idx - 65536; int n = i >> 7, k = i & 127;   // n=c 0..31
        Mkt[i] = f2bf(Mk[k * 32 + n]);
    }
}

// ---------------------------------------------------------------------------
// MFMA helper: wave computes 16 rows x (NT*16) cols, K=128.
// ---------------------------------------------------------------------------
template <int NT, class F>
__device__ __forceinline__ void mfma_phase(const unsigned short* Wlds,
                                           const s16x8 (&aF)[4], int lane, F emit)
{
    const int quad = lane >> 4, nrow = lane & 15;
#pragma unroll
    for (int nt = 0; nt < NT; ++nt) {
        f32x4 acc = {0.f, 0.f, 0.f, 0.f};
#pragma unroll
        for (int kb = 0; kb < 4; ++kb) {
            s16x8 bf = *(const s16x8*)&Wlds[(nt * 16 + nrow) * 136 + kb * 32 + quad * 8];
            acc = __builtin_amdgcn_mfma_f32_16x16x32_bf16(aF[kb], bf, acc, 0, 0, 0);
        }
        int col = nt * 16 + nrow;
        emit(quad * 4 + 0, col, acc[0]);
        emit(quad * 4 + 1, col, acc[1]);
        emit(quad * 4 + 2, col, acc[2]);
        emit(quad * 4 + 3, col, acc[3]);
    }
}

// ---------------------------------------------------------------------------
// pre_kernel (MFMA): block = 256 thr (4 waves) = 64 (b,t) rows.
//   Wo  fp32 [r][32]
//   EA2 u32, seq-friendly layout: [b][g=t/32][j4=(t%32)/4][d][sub=t%4]
//     (lo16 = et bf16, hi16 = at bf16) -> seq loads are coalesced uint4
//   Ko  bf16 [r][128]
// ---------------------------------------------------------------------------
__global__ __launch_bounds__(256) void pre_kernel(
    const int* __restrict__ skills, const int* __restrict__ responses,
    const float* __restrict__ k_emb, const float* __restrict__ v_emb,
    const float* __restrict__ fb, const float* __restrict__ eb,
    const float* __restrict__ ab,
    const unsigned short* __restrict__ Mkt, const unsigned short* __restrict__ fWbt,
    const unsigned short* __restrict__ eWt, const unsigned short* __restrict__ aWt,
    float* __restrict__ Wo, unsigned* __restrict__ EA,
    unsigned short* __restrict__ Ko, float* __restrict__ outTrue,
    int t0, int Tc)
{
    const int tid = threadIdx.x;
    const int lane = tid & 63;
    const int m_base = (tid >> 6) * 16;
    const int mrow = lane & 15, quad = lane >> 4;
    const size_t base = (size_t)blockIdx.x * 64;
    unsigned short* __restrict__ EA16 = (unsigned short*)EA;

    __shared__ __align__(16) unsigned short Albs[64 * 136];
    __shared__ __align__(16) unsigned short Wlds[128 * 136];
    __shared__ float lg[64 * 33];
    __shared__ int sIdx[64], qIdx[64];

    if (tid < 64) {
        int flat = (int)base + tid;
        int b = flat / Tc, tcc = flat % Tc;
        int t = t0 + tcc;
        int gi = b * TT + t;
        int s = skills[gi];
        int r = responses[gi];
        sIdx[tid] = s;
        qIdx[tid] = s + NQ * ((r > -1) ? r : 0);
        if (t >= 1) outTrue[b * (TT - 1) + (t - 1)] = (float)r;
    }
    __syncthreads();

    {
        int row = tid >> 2, c0 = (tid & 3) * 32;
        int s = sIdx[row];
        const float* src = k_emb + (size_t)s * DK + c0;
#pragma unroll
        for (int j = 0; j < 8; ++j) {
            float4 v = *(const float4*)(src + j * 4);
            unsigned short* dp = &Albs[row * 136 + c0 + j * 4];
            dp[0] = f2bf(v.x); dp[1] = f2bf(v.y); dp[2] = f2bf(v.z); dp[3] = f2bf(v.w);
        }
        int n = tid >> 3, k0 = (tid & 7) * 16;
        *(s16x8*)&Wlds[n * 136 + k0]     = *(const s16x8*)&Mkt[n * 128 + k0];
        *(s16x8*)&Wlds[n * 136 + k0 + 8] = *(const s16x8*)&Mkt[n * 128 + k0 + 8];
    }
    __syncthreads();

    s16x8 aF[4];
#pragma unroll
    for (int kb = 0; kb < 4; ++kb)
        aF[kb] = *(const s16x8*)&Albs[(m_base + mrow) * 136 + kb * 32 + quad * 8];
    mfma_phase<2>(Wlds, aF, lane, [&](int ml, int col, float x) {
        lg[(m_base + ml) * 33 + col] = x;
    });
    __syncthreads();

    {
        int n = tid >> 1, k0 = (tid & 1) * 64;
#pragma unroll
        for (int j = 0; j < 8; ++j)
            *(s16x8*)&Wlds[n * 136 + k0 + j * 8] = *(const s16x8*)&fWbt[n * 128 + k0 + j * 8];
    }
    if (tid < 64) {
        float m = -1e30f;
#pragma unroll
        for (int c = 0; c < CC; ++c) m = fmaxf(m, lg[tid * 33 + c]);
        float ex[CC]; float sum = 0.f;
#pragma unroll
        for (int c = 0; c < CC; ++c) { ex[c] = __expf(lg[tid * 33 + c] - m); sum += ex[c]; }
        float inv = 1.f / sum;
        float* wp = Wo + (base + tid) * CC;
#pragma unroll
        for (int c = 0; c < CC; c += 4)
            *(float4*)(wp + c) = make_float4(ex[c] * inv, ex[c + 1] * inv,
                                             ex[c + 2] * inv, ex[c + 3] * inv);
    }
    __syncthreads();

    mfma_phase<8>(Wlds, aF, lane, [&](int ml, int col, float x) {
        size_t r = base + m_base + ml;
        Ko[r * 128 + col] = f2bf(x + fb[col]);
    });
    __syncthreads();

    {
        int row = tid >> 2, c0 = (tid & 3) * 32;
        int q = qIdx[row];
        const float* src = v_emb + (size_t)q * DV + c0;
#pragma unroll
        for (int j = 0; j < 8; ++j) {
            float4 v = *(const float4*)(src + j * 4);
            unsigned short* dp = &Albs[row * 136 + c0 + j * 4];
            dp[0] = f2bf(v.x); dp[1] = f2bf(v.y); dp[2] = f2bf(v.z); dp[3] = f2bf(v.w);
        }
        int n = tid >> 1, k0 = (tid & 1) * 64;
#pragma unroll
        for (int j = 0; j < 8; ++j)
            *(s16x8*)&Wlds[n * 136 + k0 + j * 8] = *(const s16x8*)&eWt[n * 128 + k0 + j * 8];
    }
    __syncthreads();

#pragma unroll
    for (int kb = 0; kb < 4; ++kb)
        aF[kb] = *(const s16x8*)&Albs[(m_base + mrow) * 136 + kb * 32 + quad * 8];
    mfma_phase<8>(Wlds, aF, lane, [&](int ml, int col, float x) {
        size_t r = base + m_base + ml;
        int bb = (int)(r / (size_t)Tc);
        int t  = (int)(r - (size_t)bb * Tc);
        size_t o4 = (((size_t)bb * (Tc >> 5) + (t >> 5)) * 8 + ((t >> 2) & 7)) * 128 + col;
        EA16[(o4 * 4 + (t & 3)) * 2] = f2bf(fast_sigmoid(x + eb[col]));
    });
    __syncthreads();

    {
        int n = tid >> 1, k0 = (tid & 1) * 64;
#pragma unroll
        for (int j = 0; j < 8; ++j)
            *(s16x8*)&Wlds[n * 136 + k0 + j * 8] = *(const s16x8*)&aWt[n * 128 + k0 + j * 8];
    }
    __syncthreads();

    mfma_phase<8>(Wlds, aF, lane, [&](int ml, int col, float x) {
        size_t r = base + m_base + ml;
        int bb = (int)(r / (size_t)Tc);
        int t  = (int)(r - (size_t)bb * Tc);
        size_t o4 = (((size_t)bb * (Tc >> 5) + (t >> 5)) * 8 + ((t >> 2) & 7)) * 128 + col;
        EA16[(o4 * 4 + (t & 3)) * 2 + 1] = f2bf(fast_tanh(x + ab[col]));
    });
}

// ---------------------------------------------------------------------------
// seq_kernel v6: 1 block/batch, 128 thr, thread d owns Mv[:,d] (32 regs).
//
// R5 post-mortem: LDS pipe was co-bottleneck (2 waves x (8 b128 w reads +
// EA read) + 4-way-conflicted EA publish writes = 786K conflicts). v6 keeps
// ONLY w in LDS (wave-shared broadcast data, 9 KB double buffer); e/a are
// thread-private -> staged in REGISTERS via ping-pong arrays erA/erB with
// compile-time indices only (R5-proven SROA-safe pattern), loaded as
// coalesced uint4 from the seq-friendly EA2 layout one full chunk (~6000
// cyc) ahead of use.
// ---------------------------------------------------------------------------

#define CH 32
#define WROW 36     // Wl row stride (floats)

#define LOAD_W(gg) do {                                                       \
    const float* ws = Wb + (size_t)(gg) * CH * 32;                            \
    wr0 = *(const float4*)(ws + tid * 8);                                     \
    wr1 = *(const float4*)(ws + tid * 8 + 4);                                 \
} while (0)

#define PUB_W(gg) do {                                                        \
    float* wd = &Wl[(gg) & 1][lr * WROW + lq * 8];                            \
    *(float4*)wd = wr0; *(float4*)(wd + 4) = wr1;                             \
} while (0)

#define LOAD_EA(ER, gg) do {                                                  \
    const uint4* src = EA4 + ((size_t)(bq + (gg))) * 1024 + d;                \
    _Pragma("unroll")                                                         \
    for (int j = 0; j < 8; ++j) ER[j] = src[j * 128];                         \
} while (0)

#define SEQ_CHUNK(ER, gg) do {                                                \
    const float* wlc = Wl[(gg) & 1];                                          \
    _Pragma("unroll")                                                         \
    for (int tl = 0; tl < CH; ++tl) {                                         \
        const float* wrow = wlc + tl * WROW;                                  \
        float4 wv[8];                                                         \
        _Pragma("unroll")                                                     \
        for (int q = 0; q < 8; ++q) wv[q] = *(const float4*)(wrow + q * 4);   \
        unsigned ea = u4get(ER[tl >> 2], tl & 3);                             \
        float e = __uint_as_float(ea << 16);                                  \
        float a = __uint_as_float(ea & 0xffff0000u);                          \
        float r0 = 0.f, r1 = 0.f, r2 = 0.f, r3 = 0.f;                         \
        _Pragma("unroll")                                                     \
        for (int q = 0; q < 8; ++q) {                                         \
            r0 = fmaf(wv[q].x, Mv[4*q+0], r0);                                \
            r1 = fmaf(wv[q].y, Mv[4*q+1], r1);                                \
            r2 = fmaf(wv[q].z, Mv[4*q+2], r2);                                \
            r3 = fmaf(wv[q].w, Mv[4*q+3], r3);                                \
        }                                                                     \
        RTb[(size_t)((gg) * CH + tl) * 128] = f2bf((r0 + r1) + (r2 + r3));    \
        _Pragma("unroll")                                                     \
        for (int q = 0; q < 8; ++q) {                                         \
            Mv[4*q+0] = fmaf(wv[q].x, fmaf(-e, Mv[4*q+0], a), Mv[4*q+0]);     \
            Mv[4*q+1] = fmaf(wv[q].y, fmaf(-e, Mv[4*q+1], a), Mv[4*q+1]);     \
            Mv[4*q+2] = fmaf(wv[q].z, fmaf(-e, Mv[4*q+2], a), Mv[4*q+2]);     \
            Mv[4*q+3] = fmaf(wv[q].w, fmaf(-e, Mv[4*q+3], a), Mv[4*q+3]);     \
        }                                                                     \
    }                                                                         \
} while (0)

__global__ __launch_bounds__(128, 1) void seq_kernel(
    const float* __restrict__ W, const unsigned* __restrict__ EA,
    const float* __restrict__ Mv0,
    unsigned short* __restrict__ RT, float* __restrict__ MvWS,
    int Tc, int doInit, int doSave)
{
    const int b = blockIdx.x;
    const int tid = threadIdx.x;
    const int d = tid;
    const int lr = tid >> 2;            // W-publish row (0..31)
    const int lq = tid & 3;             // W-publish quarter

    __shared__ __align__(16) float Wl[2][CH * WROW];

    float Mv[32];
    if (doInit) {
#pragma unroll
        for (int c = 0; c < 32; ++c) Mv[c] = Mv0[c * 128 + d];
    } else {
#pragma unroll
        for (int c = 0; c < 32; ++c) Mv[c] = MvWS[(size_t)b * 4096 + c * 128 + d];
    }

    const float* __restrict__ Wb = W + (size_t)b * Tc * 32;
    const uint4* __restrict__ EA4 = (const uint4*)EA;
    unsigned short* __restrict__ RTb = RT + (size_t)b * Tc * 128 + d;

    const int nch = Tc / CH;
    const int bq = b * nch;             // EA chunk base index for this batch

    float4 wr0, wr1;
    uint4 erA[8], erB[8];

    // prologue: W chunk0 -> Wl[0]; EA chunk0 -> erA; W chunk1 -> regs
    LOAD_W(0);
    PUB_W(0);
    LOAD_EA(erA, 0);
    if (nch > 1) LOAD_W(1);
    __syncthreads();

    for (int g = 0; g < nch; g += 2) {
        // ---- chunk g (even): consume erA, Wl[g&1] ----
        if (g + 1 < nch) PUB_W(g + 1);
        if (g + 2 < nch) LOAD_W(g + 2);
        if (g + 1 < nch) LOAD_EA(erB, g + 1);
        SEQ_CHUNK(erA, g);
        __syncthreads();

        if (g + 1 < nch) {
            // ---- chunk g+1 (odd): consume erB, Wl[(g+1)&1] ----
            if (g + 2 < nch) PUB_W(g + 2);
            if (g + 3 < nch) LOAD_W(g + 3);
            if (g + 2 < nch) LOAD_EA(erA, g + 2);
            SEQ_CHUNK(erB, g + 1);
            __syncthreads();
        }
    }

    if (doSave) {
#pragma unroll
        for (int c = 0; c < 32; ++c) MvWS[(size_t)b * 4096 + c * 128 + d] = Mv[c];
    }
}

// ---------------------------------------------------------------------------
// post_kernel (MFMA, unchanged)
// ---------------------------------------------------------------------------
__global__ __launch_bounds__(256) void post_kernel(
    const unsigned short* __restrict__ RT, const unsigned short* __restrict__ Ko,
    const unsigned short* __restrict__ fWat, const float* __restrict__ pW,
    const float* __restrict__ pb,
    float* __restrict__ pred, int t0, int Tc)
{
    const int tid = threadIdx.x;
    const int lane = tid & 63;
    const int m_base = (tid >> 6) * 16;
    const int mrow = lane & 15, quad = lane >> 4;
    const size_t base = (size_t)blockIdx.x * 64;

    __shared__ __align__(16) unsigned short Albs[64 * 136];
    __shared__ __align__(16) unsigned short Wlds[128 * 136];

    {
        int row = tid >> 2, c0 = (tid & 3) * 32;
#pragma unroll
        for (int j = 0; j < 4; ++j)
            *(s16x8*)&Albs[row * 136 + c0 + j * 8] =
                *(const s16x8*)&RT[(base + row) * 128 + c0 + j * 8];
        int n = tid >> 1, k0 = (tid & 1) * 64;
#pragma unroll
        for (int j = 0; j < 8; ++j)
            *(s16x8*)&Wlds[n * 136 + k0 + j * 8] = *(const s16x8*)&fWat[n * 128 + k0 + j * 8];
    }
    __syncthreads();

    s16x8 aF[4];
#pragma unroll
    for (int kb = 0; kb < 4; ++kb)
        aF[kb] = *(const s16x8*)&Albs[(m_base + mrow) * 136 + kb * 32 + quad * 8];

    float p0 = 0.f, p1 = 0.f, p2 = 0.f, p3 = 0.f;
#pragma unroll
    for (int nt = 0; nt < 8; ++nt) {
        f32x4 acc = {0.f, 0.f, 0.f, 0.f};
#pragma unroll
        for (int kb = 0; kb < 4; ++kb) {
            s16x8 bf = *(const s16x8*)&Wlds[(nt * 16 + mrow) * 136 + kb * 32 + quad * 8];
            acc = __builtin_amdgcn_mfma_f32_16x16x32_bf16(aF[kb], bf, acc, 0, 0, 0);
        }
        int col = nt * 16 + mrow;
        float pw = pW[col];
        size_t rbase = base + m_base + quad * 4;
        p0 = fmaf(fast_tanh(acc[0] + bf2f(Ko[(rbase + 0) * 128 + col])), pw, p0);
        p1 = fmaf(fast_tanh(acc[1] + bf2f(Ko[(rbase + 1) * 128 + col])), pw, p1);
        p2 = fmaf(fast_tanh(acc[2] + bf2f(Ko[(rbase + 2) * 128 + col])), pw, p2);
        p3 = fmaf(fast_tanh(acc[3] + bf2f(Ko[(rbase + 3) * 128 + col])), pw, p3);
    }
#pragma unroll
    for (int off = 1; off < 16; off <<= 1) {
        p0 += __shfl_xor(p0, off, 64);
        p1 += __shfl_xor(p1, off, 64);
        p2 += __shfl_xor(p2, off, 64);
        p3 += __shfl_xor(p3, off, 64);
    }

    if (mrow == 0) {
        float pbv = pb[0];
        float ps[4] = {p0, p1, p2, p3};
#pragma unroll
        for (int reg = 0; reg < 4; ++reg) {
            int r = (int)base + m_base + quad * 4 + reg;
            int b = r / Tc, tcc = r % Tc;
            int t = t0 + tcc;
            if (t < TT - 1)
                pred[b * (TT - 1) + t] = fast_sigmoid(ps[reg] + pbv);
        }
    }
}

// ---------------------------------------------------------------------------

extern "C" void kernel_launch(void* const* d_in, const int* in_sizes, int n_in,
                              void* d_out, int out_size, void* d_ws, size_t ws_size,
                              hipStream_t stream) {
    const int*   skills    = (const int*)d_in[0];
    const int*   responses = (const int*)d_in[1];
    const float* k_emb     = (const float*)d_in[2];
    const float* v_emb     = (const float*)d_in[3];
    const float* Mk        = (const float*)d_in[4];
    const float* Mv0       = (const float*)d_in[5];
    const float* f_W       = (const float*)d_in[6];
    const float* f_b       = (const float*)d_in[7];
    const float* p_W       = (const float*)d_in[8];
    const float* p_b       = (const float*)d_in[9];
    const float* e_W       = (const float*)d_in[10];
    const float* e_b       = (const float*)d_in[11];
    const float* a_W       = (const float*)d_in[12];
    const float* a_b       = (const float*)d_in[13];

    float* pred    = (float*)d_out;                 // [256][255]
    float* outTrue = pred + BB * (TT - 1);          // [256][255]

    // scratch: Wo fp32 + EA u32 + Ko bf16 + RT bf16 (per row: 128+512+256+256 B)
    int Tc = TT;
    for (;;) {
        size_t need = (size_t)BB * Tc * 1152 + 69632 * 2;
        if (Tc < TT) need += (size_t)BB * 4096 * 4;
        if (need <= ws_size || Tc <= 32) break;
        Tc >>= 1;
    }

    char* p = (char*)d_ws;
    float* Wo = (float*)p;                 p += (size_t)BB * Tc * 32 * 4;
    unsigned* EA = (unsigned*)p;           p += (size_t)BB * Tc * 128 * 4;
    unsigned short* Ko = (unsigned short*)p;   p += (size_t)BB * Tc * 128 * 2;
    unsigned short* RT = (unsigned short*)p;   p += (size_t)BB * Tc * 128 * 2;
    unsigned short* eWt = (unsigned short*)p;  p += 16384 * 2;
    unsigned short* aWt = (unsigned short*)p;  p += 16384 * 2;
    unsigned short* fWat = (unsigned short*)p; p += 16384 * 2;
    unsigned short* fWbt = (unsigned short*)p; p += 16384 * 2;
    unsigned short* Mkt = (unsigned short*)p;  p += 4096 * 2;
    float* MvWS = (float*)p;

    conv_kernel<<<272, 256, 0, stream>>>(e_W, a_W, f_W, Mk,
                                         eWt, aWt, fWat, fWbt, Mkt);

    for (int t0 = 0; t0 < TT; t0 += Tc) {
        pre_kernel<<<(BB * Tc) / 64, 256, 0, stream>>>(
            skills, responses, k_emb, v_emb, f_b, e_b, a_b,
            Mkt, fWbt, eWt, aWt, Wo, EA, Ko, outTrue, t0, Tc);
        seq_kernel<<<BB, 128, 0, stream>>>(
            Wo, EA, Mv0, RT, MvWS,
            Tc, t0 == 0 ? 1 : 0, (t0 + Tc < TT) ? 1 : 0);
        post_kernel<<<(BB * Tc) / 64, 256, 0, stream>>>(
            RT, Ko, fWat, p_W, p_b, pred, t0, Tc);
    }
}

// Round 7
// 175.734 us; speedup vs baseline: 3.7814x; 1.1555x over previous
//
#include <hip/hip_runtime.h>
#include <math.h>

// Problem constants (fixed by setup_inputs)
#define BB 256      // batch
#define TT 256      // time steps
#define NQ 1000     // num_q
#define DK 128
#define DV 128
#define CC 32

typedef short s16x8 __attribute__((ext_vector_type(8)));   // 8 bf16 bit-patterns
typedef float f32x4 __attribute__((ext_vector_type(4)));
typedef float f32x2 __attribute__((ext_vector_type(2)));

__device__ __forceinline__ float fast_sigmoid(float x) {
    x = fminf(fmaxf(x, -30.f), 30.f);
    return 1.f / (1.f + __expf(-x));
}
__device__ __forceinline__ float fast_tanh(float x) {
    x = fminf(fmaxf(x, -15.f), 15.f);
    float t = __expf(2.f * x);
    return (t - 1.f) / (t + 1.f);
}
__device__ __forceinline__ unsigned short f2bf(float f) {   // RNE fp32->bf16
    unsigned u = __float_as_uint(f);
    u += 0x7fffu + ((u >> 16) & 1u);
    return (unsigned short)(u >> 16);
}
__device__ __forceinline__ float bf2f(unsigned short h) {
    return __uint_as_float((unsigned)h << 16);
}
__device__ __forceinline__ unsigned u4get(uint4 v, int i) { // i constant after unroll
    return i == 0 ? v.x : i == 1 ? v.y : i == 2 ? v.z : v.w;
}
__device__ __forceinline__ f32x2 mk2(float x, float y) { f32x2 r; r.x = x; r.y = y; return r; }
__device__ __forceinline__ f32x2 fma2(f32x2 a, f32x2 b, f32x2 c) {
    return __builtin_elementwise_fma(a, b, c);
}

// ---------------------------------------------------------------------------
// conv_kernel: build bf16 TRANSPOSED weights in ws (B-operand layout Wt[n][k])
// ---------------------------------------------------------------------------
__global__ __launch_bounds__(256) void conv_kernel(
    const float* __restrict__ eW, const float* __restrict__ aW,
    const float* __restrict__ fW, const float* __restrict__ Mk,
    unsigned short* __restrict__ eWt, unsigned short* __restrict__ aWt,
    unsigned short* __restrict__ fWat, unsigned short* __restrict__ fWbt,
    unsigned short* __restrict__ Mkt)
{
    int idx = blockIdx.x * 256 + threadIdx.x;
    if (idx < 16384) {
        int n = idx >> 7, k = idx & 127;
        eWt[idx] = f2bf(eW[k * 128 + n]);
    } else if (idx < 32768) {
        int i = idx - 16384; int n = i >> 7, k = i & 127;
        aWt[i] = f2bf(aW[k * 128 + n]);
    } else if (idx < 49152) {
        int i = idx - 32768; int n = i >> 7, k = i & 127;
        fWat[i] = f2bf(fW[k * 128 + n]);
    } else if (idx < 65536) {
        int i = idx - 49152; int n = i >> 7, k = i & 127;
        fWbt[i] = f2bf(fW[(128 + k) * 128 + n]);
    } else if (idx < 69632) {
        int i = idx - 65536; int n = i >> 7, k = i & 127;   // n=c 0..31
        Mkt[i] = f2bf(Mk[k * 32 + n]);
    }
}

// ---------------------------------------------------------------------------
// MFMA helper: wave computes 16 rows x (NT*16) cols, K=128.
// ---------------------------------------------------------------------------
template <int NT, class F>
__device__ __forceinline__ void mfma_phase(const unsigned short* Wlds,
                                           const s16x8 (&aF)[4], int lane, F emit)
{
    const int quad = lane >> 4, nrow = lane & 15;
#pragma unroll
    for (int nt = 0; nt < NT; ++nt) {
        f32x4 acc = {0.f, 0.f, 0.f, 0.f};
#pragma unroll
        for (int kb = 0; kb < 4; ++kb) {
            s16x8 bf = *(const s16x8*)&Wlds[(nt * 16 + nrow) * 136 + kb * 32 + quad * 8];
            acc = __builtin_amdgcn_mfma_f32_16x16x32_bf16(aF[kb], bf, acc, 0, 0, 0);
        }
        int col = nt * 16 + nrow;
        emit(quad * 4 + 0, col, acc[0]);
        emit(quad * 4 + 1, col, acc[1]);
        emit(quad * 4 + 2, col, acc[2]);
        emit(quad * 4 + 3, col, acc[3]);
    }
}

// ---------------------------------------------------------------------------
// pre_kernel (MFMA): block = 256 thr (4 waves) = 64 (b,t) rows.
//   Wo  fp32 [r][32]
//   EA  u32, seq-friendly layout: [b][g=t/32][j4=(t%32)/4][d][sub=t%4]
//     (lo16 = et bf16, hi16 = at bf16)
//   Ko  bf16 [r][128]
// R7: phase 6 parks et in Albs (vt fragments already in regs); phase 8 packs
// (et,at) into a single 4B store — halves EA global-store count.
// ---------------------------------------------------------------------------
__global__ __launch_bounds__(256) void pre_kernel(
    const int* __restrict__ skills, const int* __restrict__ responses,
    const float* __restrict__ k_emb, const float* __restrict__ v_emb,
    const float* __restrict__ fb, const float* __restrict__ eb,
    const float* __restrict__ ab,
    const unsigned short* __restrict__ Mkt, const unsigned short* __restrict__ fWbt,
    const unsigned short* __restrict__ eWt, const unsigned short* __restrict__ aWt,
    float* __restrict__ Wo, unsigned* __restrict__ EA,
    unsigned short* __restrict__ Ko, float* __restrict__ outTrue,
    int t0, int Tc)
{
    const int tid = threadIdx.x;
    const int lane = tid & 63;
    const int m_base = (tid >> 6) * 16;
    const int mrow = lane & 15, quad = lane >> 4;
    const size_t base = (size_t)blockIdx.x * 64;

    __shared__ __align__(16) unsigned short Albs[64 * 136];
    __shared__ __align__(16) unsigned short Wlds[128 * 136];
    __shared__ float lg[64 * 33];
    __shared__ int sIdx[64], qIdx[64];

    if (tid < 64) {
        int flat = (int)base + tid;
        int b = flat / Tc, tcc = flat % Tc;
        int t = t0 + tcc;
        int gi = b * TT + t;
        int s = skills[gi];
        int r = responses[gi];
        sIdx[tid] = s;
        qIdx[tid] = s + NQ * ((r > -1) ? r : 0);
        if (t >= 1) outTrue[b * (TT - 1) + (t - 1)] = (float)r;
    }
    __syncthreads();

    {
        int row = tid >> 2, c0 = (tid & 3) * 32;
        int s = sIdx[row];
        const float* src = k_emb + (size_t)s * DK + c0;
#pragma unroll
        for (int j = 0; j < 8; ++j) {
            float4 v = *(const float4*)(src + j * 4);
            unsigned short* dp = &Albs[row * 136 + c0 + j * 4];
            dp[0] = f2bf(v.x); dp[1] = f2bf(v.y); dp[2] = f2bf(v.z); dp[3] = f2bf(v.w);
        }
        int n = tid >> 3, k0 = (tid & 7) * 16;
        *(s16x8*)&Wlds[n * 136 + k0]     = *(const s16x8*)&Mkt[n * 128 + k0];
        *(s16x8*)&Wlds[n * 136 + k0 + 8] = *(const s16x8*)&Mkt[n * 128 + k0 + 8];
    }
    __syncthreads();

    s16x8 aF[4];
#pragma unroll
    for (int kb = 0; kb < 4; ++kb)
        aF[kb] = *(const s16x8*)&Albs[(m_base + mrow) * 136 + kb * 32 + quad * 8];
    mfma_phase<2>(Wlds, aF, lane, [&](int ml, int col, float x) {
        lg[(m_base + ml) * 33 + col] = x;
    });
    __syncthreads();

    {
        int n = tid >> 1, k0 = (tid & 1) * 64;
#pragma unroll
        for (int j = 0; j < 8; ++j)
            *(s16x8*)&Wlds[n * 136 + k0 + j * 8] = *(const s16x8*)&fWbt[n * 128 + k0 + j * 8];
    }
    if (tid < 64) {
        float m = -1e30f;
#pragma unroll
        for (int c = 0; c < CC; ++c) m = fmaxf(m, lg[tid * 33 + c]);
        float ex[CC]; float sum = 0.f;
#pragma unroll
        for (int c = 0; c < CC; ++c) { ex[c] = __expf(lg[tid * 33 + c] - m); sum += ex[c]; }
        float inv = 1.f / sum;
        float* wp = Wo + (base + tid) * CC;
#pragma unroll
        for (int c = 0; c < CC; c += 4)
            *(float4*)(wp + c) = make_float4(ex[c] * inv, ex[c + 1] * inv,
                                             ex[c + 2] * inv, ex[c + 3] * inv);
    }
    __syncthreads();

    mfma_phase<8>(Wlds, aF, lane, [&](int ml, int col, float x) {
        size_t r = base + m_base + ml;
        Ko[r * 128 + col] = f2bf(x + fb[col]);
    });
    __syncthreads();

    {
        int row = tid >> 2, c0 = (tid & 3) * 32;
        int q = qIdx[row];
        const float* src = v_emb + (size_t)q * DV + c0;
#pragma unroll
        for (int j = 0; j < 8; ++j) {
            float4 v = *(const float4*)(src + j * 4);
            unsigned short* dp = &Albs[row * 136 + c0 + j * 4];
            dp[0] = f2bf(v.x); dp[1] = f2bf(v.y); dp[2] = f2bf(v.z); dp[3] = f2bf(v.w);
        }
        int n = tid >> 1, k0 = (tid & 1) * 64;
#pragma unroll
        for (int j = 0; j < 8; ++j)
            *(s16x8*)&Wlds[n * 136 + k0 + j * 8] = *(const s16x8*)&eWt[n * 128 + k0 + j * 8];
    }
    __syncthreads();

#pragma unroll
    for (int kb = 0; kb < 4; ++kb)
        aF[kb] = *(const s16x8*)&Albs[(m_base + mrow) * 136 + kb * 32 + quad * 8];
    // phase 6: et -> Albs (vt frags already in regs; each wave touches only its rows)
    mfma_phase<8>(Wlds, aF, lane, [&](int ml, int col, float x) {
        Albs[(m_base + ml) * 136 + col] = f2bf(fast_sigmoid(x + eb[col]));
    });
    __syncthreads();

    {
        int n = tid >> 1, k0 = (tid & 1) * 64;
#pragma unroll
        for (int j = 0; j < 8; ++j)
            *(s16x8*)&Wlds[n * 136 + k0 + j * 8] = *(const s16x8*)&aWt[n * 128 + k0 + j * 8];
    }
    __syncthreads();

    // phase 8: at + pack(et,at) -> one 4B store
    mfma_phase<8>(Wlds, aF, lane, [&](int ml, int col, float x) {
        size_t r = base + m_base + ml;
        int bb = (int)(r / (size_t)Tc);
        int t  = (int)(r - (size_t)bb * Tc);
        size_t o4 = (((size_t)bb * (Tc >> 5) + (t >> 5)) * 8 + ((t >> 2) & 7)) * 128 + col;
        unsigned lo = Albs[(m_base + ml) * 136 + col];
        unsigned hi = (unsigned)f2bf(fast_tanh(x + ab[col])) << 16;
        EA[o4 * 4 + (t & 3)] = hi | lo;
    });
}

// ---------------------------------------------------------------------------
// fused_kernel (seq + post): 1 block/batch, 256 thr.
//   waves 0-1 (tid<128): the serial chain. thread d owns Mv[:,d] as 16
//     f32x2 (c-pairs) -> packed v_pk_fma_f32; w via LDS double-buffer;
//     EA staged in register ping-pong (R6 pattern); rt -> LDS ring (bf16).
//   waves 2-3: per chunk, ft = tanh(rt@fWa + ck) via MFMA from the rt ring
//     + p-dot + pred store — runs in the chain's latency shadow (m114:
//     MFMA/VALU waves co-schedule).
// One __syncthreads per chunk flips the 2-slot ring.
// ---------------------------------------------------------------------------

#define CH 32
#define WROW 36     // Wl row stride (floats)

#define LOAD_W(gg) do {                                                       \
    const float* ws = Wb + (size_t)(gg) * CH * 32;                            \
    wr0 = *(const float4*)(ws + tid * 8);                                     \
    wr1 = *(const float4*)(ws + tid * 8 + 4);                                 \
} while (0)

#define PUB_W(gg) do {                                                        \
    float* wd = &Wl[(gg) & 1][lr * WROW + lq * 8];                            \
    *(float4*)wd = wr0; *(float4*)(wd + 4) = wr1;                             \
} while (0)

#define LOAD_EA(ER, gg) do {                                                  \
    const uint4* src = EA4 + ((size_t)(bq + (gg))) * 1024 + tid;              \
    _Pragma("unroll")                                                         \
    for (int j = 0; j < 8; ++j) ER[j] = src[j * 128];                         \
} while (0)

#define SEQ_CHUNK(ER, gg, SL) do {                                            \
    const float* wlc = Wl[(gg) & 1];                                          \
    unsigned short* slp = SL;                                                 \
    _Pragma("unroll")                                                         \
    for (int tl = 0; tl < CH; ++tl) {                                         \
        const float* wrow = wlc + tl * WROW;                                  \
        float4 wqa = *(const float4*)(wrow + 0);                              \
        float4 wqb = *(const float4*)(wrow + 4);                              \
        float4 wqc = *(const float4*)(wrow + 8);                              \
        float4 wqd = *(const float4*)(wrow + 12);                             \
        float4 wqe = *(const float4*)(wrow + 16);                             \
        float4 wqf = *(const float4*)(wrow + 20);                             \
        float4 wqg = *(const float4*)(wrow + 24);                             \
        float4 wqh = *(const float4*)(wrow + 28);                             \
        f32x2 w2[16];                                                         \
        w2[0]  = mk2(wqa.x, wqa.y); w2[1]  = mk2(wqa.z, wqa.w);               \
        w2[2]  = mk2(wqb.x, wqb.y); w2[3]  = mk2(wqb.z, wqb.w);               \
        w2[4]  = mk2(wqc.x, wqc.y); w2[5]  = mk2(wqc.z, wqc.w);               \
        w2[6]  = mk2(wqd.x, wqd.y); w2[7]  = mk2(wqd.z, wqd.w);               \
        w2[8]  = mk2(wqe.x, wqe.y); w2[9]  = mk2(wqe.z, wqe.w);               \
        w2[10] = mk2(wqf.x, wqf.y); w2[11] = mk2(wqf.z, wqf.w);               \
        w2[12] = mk2(wqg.x, wqg.y); w2[13] = mk2(wqg.z, wqg.w);               \
        w2[14] = mk2(wqh.x, wqh.y); w2[15] = mk2(wqh.z, wqh.w);               \
        unsigned ea = u4get(ER[tl >> 2], tl & 3);                             \
        float e = __uint_as_float(ea << 16);                                  \
        float a = __uint_as_float(ea & 0xffff0000u);                          \
        f32x2 ne2 = mk2(-e, -e);                                              \
        f32x2 a2  = mk2(a, a);                                                \
        f32x2 r0 = mk2(0.f, 0.f), r1 = r0, r2 = r0, r3 = r0;                  \
        _Pragma("unroll")                                                     \
        for (int q = 0; q < 4; ++q) {                                         \
            r0 = fma2(w2[4*q+0], Mv2[4*q+0], r0);                             \
            r1 = fma2(w2[4*q+1], Mv2[4*q+1], r1);                             \
            r2 = fma2(w2[4*q+2], Mv2[4*q+2], r2);                             \
            r3 = fma2(w2[4*q+3], Mv2[4*q+3], r3);                             \
        }                                                                     \
        f32x2 rs = (r0 + r1) + (r2 + r3);                                     \
        slp[tl * 136 + tid] = f2bf(rs.x + rs.y);                              \
        _Pragma("unroll")                                                     \
        for (int i = 0; i < 16; ++i)                                          \
            Mv2[i] = fma2(w2[i], fma2(ne2, Mv2[i], a2), Mv2[i]);              \
    }                                                                         \
} while (0)

__device__ __forceinline__ void consume_chunk(
    int gc, const unsigned short* sl, const unsigned short* fWl,
    int b, int Tc, int t0,
    const unsigned short* __restrict__ Ko, const float* __restrict__ pW,
    float pbv, float* __restrict__ pred, int tid)
{
    const int lane = tid & 63;
    const int cw = (tid >> 6) & 1;          // consumer wave 0/1 -> rows cw*16..+15
    const int mrow = lane & 15, quad = lane >> 4;
    s16x8 aF[4];
#pragma unroll
    for (int kb = 0; kb < 4; ++kb)
        aF[kb] = *(const s16x8*)&sl[(cw * 16 + mrow) * 136 + kb * 32 + quad * 8];
    float p0 = 0.f, p1 = 0.f, p2 = 0.f, p3 = 0.f;
    size_t rbase = (size_t)b * Tc + gc * CH + cw * 16 + quad * 4;
#pragma unroll
    for (int nt = 0; nt < 8; ++nt) {
        f32x4 acc = {0.f, 0.f, 0.f, 0.f};
#pragma unroll
        for (int kb = 0; kb < 4; ++kb) {
            s16x8 bf = *(const s16x8*)&fWl[(nt * 16 + mrow) * 136 + kb * 32 + quad * 8];
            acc = __builtin_amdgcn_mfma_f32_16x16x32_bf16(aF[kb], bf, acc, 0, 0, 0);
        }
        int col = nt * 16 + mrow;
        float pw = pW[col];
        p0 = fmaf(fast_tanh(acc[0] + bf2f(Ko[(rbase + 0) * 128 + col])), pw, p0);
        p1 = fmaf(fast_tanh(acc[1] + bf2f(Ko[(rbase + 1) * 128 + col])), pw, p1);
        p2 = fmaf(fast_tanh(acc[2] + bf2f(Ko[(rbase + 2) * 128 + col])), pw, p2);
        p3 = fmaf(fast_tanh(acc[3] + bf2f(Ko[(rbase + 3) * 128 + col])), pw, p3);
    }
#pragma unroll
    for (int off = 1; off < 16; off <<= 1) {
        p0 += __shfl_xor(p0, off, 64); p1 += __shfl_xor(p1, off, 64);
        p2 += __shfl_xor(p2, off, 64); p3 += __shfl_xor(p3, off, 64);
    }
    if (mrow == 0) {
        int tb = t0 + gc * CH + cw * 16 + quad * 4;
        float ps[4] = {p0, p1, p2, p3};
#pragma unroll
        for (int reg = 0; reg < 4; ++reg) {
            int t = tb + reg;
            if (t < TT - 1) pred[b * (TT - 1) + t] = fast_sigmoid(ps[reg] + pbv);
        }
    }
}

__global__ __launch_bounds__(256, 1) void fused_kernel(
    const float* __restrict__ W, const unsigned* __restrict__ EA,
    const float* __restrict__ Mv0, const unsigned short* __restrict__ Ko,
    const unsigned short* __restrict__ fWat, const float* __restrict__ pW,
    const float* __restrict__ pb,
    float* __restrict__ pred, float* __restrict__ MvWS,
    int t0, int Tc, int doInit, int doSave)
{
    const int b = blockIdx.x;
    const int tid = threadIdx.x;
    const int nch = Tc / CH;

    __shared__ __align__(16) float Wl[2][CH * WROW];           //  9.2 KB
    __shared__ __align__(16) unsigned short rtl[2][CH * 136];  // 17.4 KB
    __shared__ __align__(16) unsigned short fWl[128 * 136];    // 34.8 KB

    // stage fWat -> fWl (all 256 threads)
    {
        int n = tid >> 1, k0 = (tid & 1) * 64;
#pragma unroll
        for (int j = 0; j < 8; ++j)
            *(s16x8*)&fWl[n * 136 + k0 + j * 8] = *(const s16x8*)&fWat[n * 128 + k0 + j * 8];
    }

    const int lr = tid >> 2, lq = tid & 3;
    const float* __restrict__ Wb = W + (size_t)b * Tc * 32;
    const uint4* __restrict__ EA4 = (const uint4*)EA;
    const int bq = b * nch;
    f32x2 Mv2[16];
    float4 wr0, wr1;
    uint4 erA[8], erB[8];
    float pbv = 0.f;

    if (tid < 128) {
        if (doInit) {
#pragma unroll
            for (int i = 0; i < 16; ++i)
                Mv2[i] = mk2(Mv0[(2 * i) * 128 + tid], Mv0[(2 * i + 1) * 128 + tid]);
        } else {
#pragma unroll
            for (int i = 0; i < 16; ++i)
                Mv2[i] = mk2(MvWS[(size_t)b * 4096 + (2 * i) * 128 + tid],
                             MvWS[(size_t)b * 4096 + (2 * i + 1) * 128 + tid]);
        }
        LOAD_W(0); PUB_W(0);
        LOAD_EA(erA, 0);
        if (nch > 1) LOAD_W(1);
    } else {
        pbv = pb[0];
    }
    __syncthreads();

    for (int g = 0; g < nch; g += 2) {
        // ---- even chunk g: produce -> slot0; consume chunk g-1 (slot1) ----
        if (tid < 128) {
            if (g + 1 < nch) PUB_W(g + 1);
            if (g + 2 < nch) LOAD_W(g + 2);
            if (g + 1 < nch) LOAD_EA(erB, g + 1);
            SEQ_CHUNK(erA, g, rtl[0]);
        } else if (g >= 1) {
            consume_chunk(g - 1, rtl[1], fWl, b, Tc, t0, Ko, pW, pbv, pred, tid);
        }
        __syncthreads();

        // ---- odd chunk g+1: produce -> slot1; consume chunk g (slot0) ----
        if (tid < 128) {
            if (g + 1 < nch) {
                if (g + 2 < nch) PUB_W(g + 2);
                if (g + 3 < nch) LOAD_W(g + 3);
                if (g + 2 < nch) LOAD_EA(erA, g + 2);
                SEQ_CHUNK(erB, g + 1, rtl[1]);
            }
        } else {
            consume_chunk(g, rtl[0], fWl, b, Tc, t0, Ko, pW, pbv, pred, tid);
        }
        __syncthreads();
    }
    // epilogue: for even nch the last (odd) chunk is still unconsumed
    if (!(nch & 1) && tid >= 128) {
        consume_chunk(nch - 1, rtl[1], fWl, b, Tc, t0, Ko, pW, pbv, pred, tid);
    }

    if (doSave && tid < 128) {
#pragma unroll
        for (int i = 0; i < 16; ++i) {
            MvWS[(size_t)b * 4096 + (2 * i) * 128 + tid]     = Mv2[i].x;
            MvWS[(size_t)b * 4096 + (2 * i + 1) * 128 + tid] = Mv2[i].y;
        }
    }
}

// ---------------------------------------------------------------------------

extern "C" void kernel_launch(void* const* d_in, const int* in_sizes, int n_in,
                              void* d_out, int out_size, void* d_ws, size_t ws_size,
                              hipStream_t stream) {
    const int*   skills    = (const int*)d_in[0];
    const int*   responses = (const int*)d_in[1];
    const float* k_emb     = (const float*)d_in[2];
    const float* v_emb     = (const float*)d_in[3];
    const float* Mk        = (const float*)d_in[4];
    const float* Mv0       = (const float*)d_in[5];
    const float* f_W       = (const float*)d_in[6];
    const float* f_b       = (const float*)d_in[7];
    const float* p_W       = (const float*)d_in[8];
    const float* p_b       = (const float*)d_in[9];
    const float* e_W       = (const float*)d_in[10];
    const float* e_b       = (const float*)d_in[11];
    const float* a_W       = (const float*)d_in[12];
    const float* a_b       = (const float*)d_in[13];

    float* pred    = (float*)d_out;                 // [256][255]
    float* outTrue = pred + BB * (TT - 1);          // [256][255]

    // scratch per row: Wo 128 B + EA 512 B + Ko 256 B = 896 B
    int Tc = TT;
    for (;;) {
        size_t need = (size_t)BB * Tc * 896 + 69632 * 2;
        if (Tc < TT) need += (size_t)BB * 4096 * 4;
        if (need <= ws_size || Tc <= 32) break;
        Tc >>= 1;
    }

    char* p = (char*)d_ws;
    float* Wo = (float*)p;                     p += (size_t)BB * Tc * 32 * 4;
    unsigned* EA = (unsigned*)p;               p += (size_t)BB * Tc * 128 * 4;
    unsigned short* Ko = (unsigned short*)p;   p += (size_t)BB * Tc * 128 * 2;
    unsigned short* eWt = (unsigned short*)p;  p += 16384 * 2;
    unsigned short* aWt = (unsigned short*)p;  p += 16384 * 2;
    unsigned short* fWat = (unsigned short*)p; p += 16384 * 2;
    unsigned short* fWbt = (unsigned short*)p; p += 16384 * 2;
    unsigned short* Mkt = (unsigned short*)p;  p += 4096 * 2;
    float* MvWS = (float*)p;

    conv_kernel<<<272, 256, 0, stream>>>(e_W, a_W, f_W, Mk,
                                         eWt, aWt, fWat, fWbt, Mkt);

    for (int t0 = 0; t0 < TT; t0 += Tc) {
        pre_kernel<<<(BB * Tc) / 64, 256, 0, stream>>>(
            skills, responses, k_emb, v_emb, f_b, e_b, a_b,
            Mkt, fWbt, eWt, aWt, Wo, EA, Ko, outTrue, t0, Tc);
        fused_kernel<<<BB, 256, 0, stream>>>(
            Wo, EA, Mv0, Ko, fWat, p_W, p_b, pred, MvWS,
            t0, Tc, t0 == 0 ? 1 : 0, (t0 + Tc < TT) ? 1 : 0);
    }
}